// Round 1
// baseline (2094.643 us; speedup 1.0000x reference)
//
#include <hip/hip_runtime.h>

#define NSRC 100000
#define NSEN 306
#define NT 256
#define NF 8
#define NH 128
#define NL 3
#define NE 600000
#define JITERS 16

// ---------------- G = L * L^T (split-K, fp32 atomics) ----------------
__global__ __launch_bounds__(256) void k_gram(const float* __restrict__ L, float* __restrict__ G) {
    __shared__ __align__(16) float As[16][68];
    __shared__ __align__(16) float Bs[16][68];
    const int bi = blockIdx.x / 5, bj = blockIdx.x % 5;
    const int i0 = bi * 64, j0 = bj * 64;
    const int k0 = blockIdx.y * 2048;
    const int kend = (k0 + 2048 < NSRC) ? (k0 + 2048) : NSRC;
    const int tid = threadIdx.x;
    const int tx = tid & 15, ty = tid >> 4;
    const int lr = tid >> 2;          // 0..63
    const int lc = (tid & 3) << 2;    // 0,4,8,12

    float acc[4][4] = {};

    for (int ks = k0; ks < kend; ks += 16) {
        float4 av = make_float4(0.f, 0.f, 0.f, 0.f);
        float4 bv = make_float4(0.f, 0.f, 0.f, 0.f);
        if (i0 + lr < NSEN) av = *(const float4*)(L + (size_t)(i0 + lr) * NSRC + ks + lc);
        if (j0 + lr < NSEN) bv = *(const float4*)(L + (size_t)(j0 + lr) * NSRC + ks + lc);
        __syncthreads();
        As[lc + 0][lr] = av.x; As[lc + 1][lr] = av.y; As[lc + 2][lr] = av.z; As[lc + 3][lr] = av.w;
        Bs[lc + 0][lr] = bv.x; Bs[lc + 1][lr] = bv.y; Bs[lc + 2][lr] = bv.z; Bs[lc + 3][lr] = bv.w;
        __syncthreads();
        #pragma unroll
        for (int kk = 0; kk < 16; ++kk) {
            float4 a = *(const float4*)&As[kk][ty * 4];
            float4 b = *(const float4*)&Bs[kk][tx * 4];
            float aa[4] = {a.x, a.y, a.z, a.w};
            float bb[4] = {b.x, b.y, b.z, b.w};
            #pragma unroll
            for (int r = 0; r < 4; ++r)
                #pragma unroll
                for (int c = 0; c < 4; ++c)
                    acc[r][c] = fmaf(aa[r], bb[c], acc[r][c]);
        }
    }
    #pragma unroll
    for (int r = 0; r < 4; ++r) {
        int gi = i0 + ty * 4 + r;
        if (gi >= NSEN) continue;
        #pragma unroll
        for (int c = 0; c < 4; ++c) {
            int gj = j0 + tx * 4 + c;
            if (gj < NSEN) atomicAdd(&G[gi * NSEN + gj], acc[r][c]);
        }
    }
}

__global__ void k_regdiag(float* __restrict__ G) {
    int i = blockIdx.x * blockDim.x + threadIdx.x;
    if (i < NSEN) G[i * NSEN + i] += 1e-6f;  // reg^2; numerically nil vs ~1e5 diag
}

// ---------------- Jacobi solve (G X = Y), X is 306x256 ----------------
__global__ __launch_bounds__(256) void k_jinit(const float* __restrict__ Y, const float* __restrict__ G,
                                               float* __restrict__ X) {
    int i = blockIdx.x, t = threadIdx.x;
    X[i * NT + t] = Y[i * NT + t] / G[i * NSEN + i];
}

__global__ __launch_bounds__(256) void k_jacobi(const float* __restrict__ G, const float* __restrict__ Y,
                                                const float* __restrict__ Xin, float* __restrict__ Xout) {
    int i = blockIdx.x, t = threadIdx.x;
    const float* g = G + (size_t)i * NSEN;
    float acc = Y[i * NT + t];
    #pragma unroll 2
    for (int k = 0; k < NSEN; ++k) acc = fmaf(-g[k], Xin[k * NT + t], acc);
    Xout[i * NT + t] = Xin[i * NT + t] + acc / g[i];
}

// ---------------- Z = X * W_in[:, :256]^T  (306 x 128) ----------------
__global__ __launch_bounds__(128) void k_Z(const float* __restrict__ X, const float* __restrict__ W_in,
                                           float* __restrict__ Z) {
    __shared__ float xs[NT];
    int i = blockIdx.x, h = threadIdx.x;
    xs[h] = X[i * NT + h];
    xs[h + 128] = X[i * NT + h + 128];
    __syncthreads();
    const float* w = W_in + (size_t)h * (NT + NF);
    float acc = 0.f;
    #pragma unroll 4
    for (int t = 0; t < NT; ++t) acc = fmaf(xs[t], w[t], acc);
    Z[i * NH + h] = acc;
}

// ------- x0 = L^T Z + vf * W_in[:,256:]^T + b_in  (100000 x 128) -------
__global__ __launch_bounds__(256) void k_x0(const float* __restrict__ L, const float* __restrict__ Z,
                                            const float* __restrict__ vf, const float* __restrict__ W_in,
                                            const float* __restrict__ b_in, float* __restrict__ x0) {
    __shared__ __align__(16) float As[16][132];
    __shared__ __align__(16) float Bs[16][132];
    __shared__ float bin_s[NH];
    __shared__ float wf_s[NH][NF];
    const int tid = threadIdx.x;
    const int n0 = blockIdx.x * 128;
    const int tx = tid & 15, ty = tid >> 4;

    if (tid < NH) bin_s[tid] = b_in[tid];
    for (int idx = tid; idx < NH * NF; idx += 256)
        wf_s[idx >> 3][idx & 7] = W_in[(size_t)(idx >> 3) * (NT + NF) + NT + (idx & 7)];

    float acc[8][8] = {};

    for (int s0 = 0; s0 < NSEN; s0 += 16) {
        __syncthreads();
        #pragma unroll
        for (int q = 0; q < 2; ++q) {
            int idx = tid * 2 + q;
            int kk = idx >> 5;
            int c4 = (idx & 31) << 2;
            float4 a = make_float4(0.f, 0.f, 0.f, 0.f);
            float4 b = make_float4(0.f, 0.f, 0.f, 0.f);
            if (s0 + kk < NSEN) {
                if (n0 + c4 < NSRC) a = *(const float4*)(L + (size_t)(s0 + kk) * NSRC + n0 + c4);
                b = *(const float4*)(Z + (size_t)(s0 + kk) * NH + c4);
            }
            *(float4*)&As[kk][c4] = a;
            *(float4*)&Bs[kk][c4] = b;
        }
        __syncthreads();
        #pragma unroll
        for (int kk = 0; kk < 16; ++kk) {
            float4 a0 = *(const float4*)&As[kk][ty * 8];
            float4 a1 = *(const float4*)&As[kk][ty * 8 + 4];
            float4 b0 = *(const float4*)&Bs[kk][tx * 8];
            float4 b1 = *(const float4*)&Bs[kk][tx * 8 + 4];
            float aa[8] = {a0.x, a0.y, a0.z, a0.w, a1.x, a1.y, a1.z, a1.w};
            float bb[8] = {b0.x, b0.y, b0.z, b0.w, b1.x, b1.y, b1.z, b1.w};
            #pragma unroll
            for (int r = 0; r < 8; ++r)
                #pragma unroll
                for (int c = 0; c < 8; ++c)
                    acc[r][c] = fmaf(aa[r], bb[c], acc[r][c]);
        }
    }
    #pragma unroll
    for (int r = 0; r < 8; ++r) {
        int n = n0 + ty * 8 + r;
        if (n >= NSRC) continue;
        float vfr[NF];
        #pragma unroll
        for (int f = 0; f < NF; ++f) vfr[f] = vf[(size_t)n * NF + f];
        float* dst = x0 + (size_t)n * NH + tx * 8;
        #pragma unroll
        for (int c = 0; c < 8; ++c) {
            int h = tx * 8 + c;
            float v = acc[r][c] + bin_s[h];
            #pragma unroll
            for (int f = 0; f < NF; ++f) v = fmaf(vfr[f], wf_s[h][f], v);
            dst[c] = v;
        }
    }
}

// ---------------- CSR build ----------------
__global__ void k_hist(const int* __restrict__ recv, int* __restrict__ cnt) {
    int e = blockIdx.x * 256 + threadIdx.x;
    if (e < NE) atomicAdd(&cnt[recv[e]], 1);
}

__global__ __launch_bounds__(1024) void k_scan(const int* __restrict__ cnt, int* __restrict__ rowptr) {
    __shared__ int sd[1024];
    const int tid = threadIdx.x;
    int running = 0;
    for (int base = 0; base < NSRC; base += 8192) {
        int off = base + tid * 8;
        int v[8];
        int s = 0;
        #pragma unroll
        for (int j = 0; j < 8; ++j) {
            v[j] = (off + j < NSRC) ? cnt[off + j] : 0;
            s += v[j];
        }
        __syncthreads();
        sd[tid] = s;
        __syncthreads();
        for (int d = 1; d < 1024; d <<= 1) {
            int add = (tid >= d) ? sd[tid - d] : 0;
            __syncthreads();
            sd[tid] += add;
            __syncthreads();
        }
        int excl = running + sd[tid] - s;
        int total = sd[1023];
        int run = excl;
        #pragma unroll
        for (int j = 0; j < 8; ++j) {
            if (off + j < NSRC) rowptr[off + j] = run;
            run += v[j];
        }
        running += total;
    }
    if (tid == 0) rowptr[NSRC] = running;
}

__global__ void k_fill(const int* __restrict__ send, const int* __restrict__ recv,
                       int* __restrict__ cursor, int* __restrict__ csr) {
    int e = blockIdx.x * 256 + threadIdx.x;
    if (e < NE) {
        int pos = atomicAdd(&cursor[recv[e]], 1);
        csr[pos] = send[e];
    }
}

// ------------- mean aggregation (pull, 1 wave per node) -------------
__global__ __launch_bounds__(256) void k_agg(const float* __restrict__ x, const int* __restrict__ rowptr,
                                             const int* __restrict__ csr, float* __restrict__ mean) {
    const int lane = threadIdx.x & 63;
    const int n = blockIdx.x * 4 + (threadIdx.x >> 6);
    if (n >= NSRC) return;
    const int beg = rowptr[n], end = rowptr[n + 1];
    float2 acc = make_float2(0.f, 0.f);
    for (int e = beg; e < end; ++e) {
        int s = csr[e];
        float2 v = *(const float2*)(x + (size_t)s * NH + lane * 2);
        acc.x += v.x; acc.y += v.y;
    }
    int d = end - beg;
    float inv = 1.f / (float)(d > 0 ? d : 1);
    float2 o; o.x = acc.x * inv; o.y = acc.y * inv;
    *(float2*)(mean + (size_t)n * NH + lane * 2) = o;
}

// ------- xnext = relu(x*Ws + mean*Wm + b), K=256, in-place over mean -------
__global__ __launch_bounds__(256) void k_gcn(const float* __restrict__ x, const float* __restrict__ mean,
                                             const float* __restrict__ Ws, const float* __restrict__ Wm,
                                             const float* __restrict__ b, float* __restrict__ out) {
    __shared__ __align__(16) float As[16][132];
    __shared__ __align__(16) float Bs[16][132];
    __shared__ float bs[NH];
    const int tid = threadIdx.x;
    const int n0 = blockIdx.x * 128;
    const int tx = tid & 15, ty = tid >> 4;
    if (tid < NH) bs[tid] = b[tid];

    float acc[8][8] = {};

    for (int kc = 0; kc < 2 * NH; kc += 16) {
        const float* Asrc = (kc < NH) ? x : mean;
        const float* Wsrc = (kc < NH) ? Ws : Wm;
        const int kcl = kc & (NH - 1);
        __syncthreads();
        #pragma unroll
        for (int q = 0; q < 2; ++q) {
            int idx = tid * 2 + q;
            int nl = idx >> 2, ac4 = (idx & 3) << 2;
            float4 a = make_float4(0.f, 0.f, 0.f, 0.f);
            if (n0 + nl < NSRC) a = *(const float4*)(Asrc + (size_t)(n0 + nl) * NH + kcl + ac4);
            As[ac4 + 0][nl] = a.x; As[ac4 + 1][nl] = a.y; As[ac4 + 2][nl] = a.z; As[ac4 + 3][nl] = a.w;
            int kk = idx >> 5, h4 = (idx & 31) << 2;
            float4 bv = *(const float4*)(Wsrc + (size_t)(kcl + kk) * NH + h4);
            *(float4*)&Bs[kk][h4] = bv;
        }
        __syncthreads();
        #pragma unroll
        for (int kk = 0; kk < 16; ++kk) {
            float4 a0 = *(const float4*)&As[kk][ty * 8];
            float4 a1 = *(const float4*)&As[kk][ty * 8 + 4];
            float4 b0 = *(const float4*)&Bs[kk][tx * 8];
            float4 b1 = *(const float4*)&Bs[kk][tx * 8 + 4];
            float aa[8] = {a0.x, a0.y, a0.z, a0.w, a1.x, a1.y, a1.z, a1.w};
            float bb[8] = {b0.x, b0.y, b0.z, b0.w, b1.x, b1.y, b1.z, b1.w};
            #pragma unroll
            for (int r = 0; r < 8; ++r)
                #pragma unroll
                for (int c = 0; c < 8; ++c)
                    acc[r][c] = fmaf(aa[r], bb[c], acc[r][c]);
        }
    }
    #pragma unroll
    for (int r = 0; r < 8; ++r) {
        int n = n0 + ty * 8 + r;
        if (n >= NSRC) continue;
        float* dst = out + (size_t)n * NH + tx * 8;
        #pragma unroll
        for (int c = 0; c < 8; ++c) {
            float v = acc[r][c] + bs[tx * 8 + c];
            dst[c] = fmaxf(v, 0.f);
        }
    }
}

// ---------------- J = x * W_out^T + b_out ----------------
__global__ __launch_bounds__(256) void k_out(const float* __restrict__ x, const float* __restrict__ Wout,
                                             const float* __restrict__ bout, float* __restrict__ J) {
    __shared__ __align__(16) float As[16][132];
    __shared__ __align__(16) float Bs[16][132];
    __shared__ float bs[128];
    const int tid = threadIdx.x;
    const int n0 = blockIdx.x * 128;
    const int t0 = blockIdx.y * 128;
    const int tx = tid & 15, ty = tid >> 4;
    if (tid < 128) bs[tid] = bout[t0 + tid];

    float acc[8][8] = {};

    for (int kc = 0; kc < NH; kc += 16) {
        __syncthreads();
        #pragma unroll
        for (int q = 0; q < 2; ++q) {
            int idx = tid * 2 + q;
            int nl = idx >> 2, c4 = (idx & 3) << 2;
            float4 a = make_float4(0.f, 0.f, 0.f, 0.f);
            if (n0 + nl < NSRC) a = *(const float4*)(x + (size_t)(n0 + nl) * NH + kc + c4);
            As[c4 + 0][nl] = a.x; As[c4 + 1][nl] = a.y; As[c4 + 2][nl] = a.z; As[c4 + 3][nl] = a.w;
            float4 b = *(const float4*)(Wout + (size_t)(t0 + nl) * NH + kc + c4);
            Bs[c4 + 0][nl] = b.x; Bs[c4 + 1][nl] = b.y; Bs[c4 + 2][nl] = b.z; Bs[c4 + 3][nl] = b.w;
        }
        __syncthreads();
        #pragma unroll
        for (int kk = 0; kk < 16; ++kk) {
            float4 a0 = *(const float4*)&As[kk][ty * 8];
            float4 a1 = *(const float4*)&As[kk][ty * 8 + 4];
            float4 b0 = *(const float4*)&Bs[kk][tx * 8];
            float4 b1 = *(const float4*)&Bs[kk][tx * 8 + 4];
            float aa[8] = {a0.x, a0.y, a0.z, a0.w, a1.x, a1.y, a1.z, a1.w};
            float bb[8] = {b0.x, b0.y, b0.z, b0.w, b1.x, b1.y, b1.z, b1.w};
            #pragma unroll
            for (int r = 0; r < 8; ++r)
                #pragma unroll
                for (int c = 0; c < 8; ++c)
                    acc[r][c] = fmaf(aa[r], bb[c], acc[r][c]);
        }
    }
    #pragma unroll
    for (int r = 0; r < 8; ++r) {
        int n = n0 + ty * 8 + r;
        if (n >= NSRC) continue;
        float* dst = J + (size_t)n * NT + t0 + tx * 8;
        #pragma unroll
        for (int c = 0; c < 8; ++c) dst[c] = acc[r][c] + bs[tx * 8 + c];
    }
}

extern "C" void kernel_launch(void* const* d_in, const int* in_sizes, int n_in,
                              void* d_out, int out_size, void* d_ws, size_t ws_size,
                              hipStream_t stream) {
    const float* Y      = (const float*)d_in[0];
    const float* L      = (const float*)d_in[1];
    const float* vf     = (const float*)d_in[2];
    const int*   send   = (const int*)d_in[3];
    const int*   recv   = (const int*)d_in[4];
    const float* W_in   = (const float*)d_in[5];
    const float* b_in   = (const float*)d_in[6];
    const float* W_self = (const float*)d_in[7];
    const float* W_msg  = (const float*)d_in[8];
    const float* b_lay  = (const float*)d_in[9];
    const float* W_out  = (const float*)d_in[10];
    const float* b_out  = (const float*)d_in[11];
    float* out = (float*)d_out;

    char* ws = (char*)d_ws;
    size_t off = 0;
    auto alloc = [&](size_t bytes) -> void* {
        void* p = ws + off;
        off += (bytes + 255) & ~(size_t)255;
        return p;
    };
    float* bufB = (float*)alloc((size_t)NSRC * NH * 4);
    float* G    = (float*)alloc((size_t)NSEN * NSEN * 4);
    float* Xa   = (float*)alloc((size_t)NSEN * NT * 4);
    float* Xb   = (float*)alloc((size_t)NSEN * NT * 4);
    float* Z    = (float*)alloc((size_t)NSEN * NH * 4);
    int* rowptr = (int*)alloc((size_t)(NSRC + 1) * 4);
    int* cursor = (int*)alloc((size_t)NSRC * 4);
    int* cnt    = (int*)alloc((size_t)NSRC * 4);
    int* csr    = (int*)alloc((size_t)NE * 4);
    // bufA lives in d_out's first half (d_out is 102.4MB, bufA is 51.2MB).
    // Final k_out reads only bufB, so overwriting d_out at the end is safe.
    float* bufA = out;

    hipMemsetAsync(G, 0, (size_t)NSEN * NSEN * 4, stream);
    hipMemsetAsync(cnt, 0, (size_t)NSRC * 4, stream);

    k_gram<<<dim3(25, 49), 256, 0, stream>>>(L, G);
    k_regdiag<<<2, 256, 0, stream>>>(G);
    k_jinit<<<NSEN, NT, 0, stream>>>(Y, G, Xa);
    float* xi = Xa;
    float* xo = Xb;
    for (int it = 0; it < JITERS; ++it) {
        k_jacobi<<<NSEN, NT, 0, stream>>>(G, Y, xi, xo);
        float* t = xi; xi = xo; xo = t;
    }
    k_Z<<<NSEN, NH, 0, stream>>>(xi, W_in, Z);
    k_x0<<<(NSRC + 127) / 128, 256, 0, stream>>>(L, Z, vf, W_in, b_in, bufA);

    k_hist<<<(NE + 255) / 256, 256, 0, stream>>>(recv, cnt);
    k_scan<<<1, 1024, 0, stream>>>(cnt, rowptr);
    hipMemcpyAsync(cursor, rowptr, (size_t)NSRC * 4, hipMemcpyDeviceToDevice, stream);
    k_fill<<<(NE + 255) / 256, 256, 0, stream>>>(send, recv, cursor, csr);

    float* x = bufA;
    float* m = bufB;
    for (int l = 0; l < NL; ++l) {
        k_agg<<<(NSRC + 3) / 4, 256, 0, stream>>>(x, rowptr, csr, m);
        k_gcn<<<(NSRC + 127) / 128, 256, 0, stream>>>(
            x, m, W_self + (size_t)l * NH * NH, W_msg + (size_t)l * NH * NH, b_lay + (size_t)l * NH, m);
        float* t = x; x = m; m = t;
    }
    k_out<<<dim3((NSRC + 127) / 128, 2), 256, 0, stream>>>(x, W_out, b_out, out);
}

// Round 4
// 955.882 us; speedup vs baseline: 2.1913x; 2.1913x over previous
//
#include <hip/hip_runtime.h>

#define NSRC 100000
#define NSEN 306
#define NT 256
#define NF 8
#define NH 128
#define NL 3
#define NE 600000
#define JITERS 10

#define GP_SPLIT 125
#define GP_CHUNK 800   // 125*800 = 100000 exactly

typedef short short8 __attribute__((ext_vector_type(8)));
typedef float f32x4 __attribute__((ext_vector_type(4)));

__device__ __forceinline__ short f2b(float f) {
    union { float f; unsigned u; } v; v.f = f;
    unsigned r = v.u + 0x7fffu + ((v.u >> 16) & 1u);
    return (short)(r >> 16);
}
__device__ __forceinline__ float b2f(unsigned short s) {
    union { unsigned u; float f; } v; v.u = ((unsigned)s) << 16;
    return v.f;
}

// ============ gram phase 1: Gp[p] = L[:,chunk_p] * L[:,chunk_p]^T (bf16 MFMA) ============
__global__ __launch_bounds__(512) void k_gram_p1(const float* __restrict__ L, float* __restrict__ Gp) {
    __shared__ short T[320 * 72];  // rows 0..319 of L (bf16), 64 k-cols, pad stride 72
    const int bid = blockIdx.x;
    const int g = bid >> 4, r = bid & 15;
    const int p = g * 8 + (r & 7);          // k-chunk index
    if (p >= GP_SPLIT) return;
    const int bi = r >> 3;                  // row half: 0 or 1
    const int c0 = p * GP_CHUNK;
    const int cend = c0 + GP_CHUNK;
    const int tid = threadIdx.x;
    const int lane = tid & 63, wid = tid >> 6;
    const int wr = wid >> 2, wc = wid & 3;  // 2x4 waves, each 80x80

    f32x4 acc[5][5] = {};

    for (int s0 = c0; s0 < cend; s0 += 64) {
        __syncthreads();
        for (int task = tid; task < 640; task += 512) {
            const int row = task >> 1, half = task & 1;
            const int col = s0 + half * 32;
            const bool ok = (row < NSEN) && (col + 31 < cend);
            const float* src = L + (size_t)row * NSRC + col;
            #pragma unroll
            for (int q = 0; q < 4; ++q) {
                float4 f0 = make_float4(0.f, 0.f, 0.f, 0.f);
                float4 f1 = make_float4(0.f, 0.f, 0.f, 0.f);
                if (ok) { f0 = *(const float4*)(src + q * 8); f1 = *(const float4*)(src + q * 8 + 4); }
                short8 t;
                t[0] = f2b(f0.x); t[1] = f2b(f0.y); t[2] = f2b(f0.z); t[3] = f2b(f0.w);
                t[4] = f2b(f1.x); t[5] = f2b(f1.y); t[6] = f2b(f1.z); t[7] = f2b(f1.w);
                *(short8*)&T[row * 72 + half * 32 + q * 8] = t;
            }
        }
        __syncthreads();
        #pragma unroll
        for (int ks = 0; ks < 2; ++ks) {
            const int kb = ks * 32 + (lane >> 4) * 8;
            short8 a[5], b[5];
            #pragma unroll
            for (int i = 0; i < 5; ++i) {
                a[i] = *(const short8*)&T[(bi * 160 + wr * 80 + i * 16 + (lane & 15)) * 72 + kb];
                b[i] = *(const short8*)&T[(wc * 80 + i * 16 + (lane & 15)) * 72 + kb];
            }
            #pragma unroll
            for (int i = 0; i < 5; ++i)
                #pragma unroll
                for (int j = 0; j < 5; ++j)
                    acc[i][j] = __builtin_amdgcn_mfma_f32_16x16x32_bf16(a[i], b[j], acc[i][j], 0, 0, 0);
        }
    }
    float* dst = Gp + (size_t)p * 320 * 320;
    #pragma unroll
    for (int i = 0; i < 5; ++i)
        #pragma unroll
        for (int j = 0; j < 5; ++j) {
            const int gj = wc * 80 + j * 16 + (lane & 15);
            #pragma unroll
            for (int rr = 0; rr < 4; ++rr) {
                const int gi = bi * 160 + wr * 80 + i * 16 + (lane >> 4) * 4 + rr;
                dst[gi * 320 + gj] = acc[i][j][rr];
            }
        }
}

// ============ gram phase 2: G = sum_p Gp[p], + reg^2 on diag ============
__global__ void k_gram_p2(const float* __restrict__ Gp, float* __restrict__ G) {
    const int idx = blockIdx.x * 256 + threadIdx.x;
    if (idx >= 320 * 320) return;
    float s = 0.f;
    for (int p = 0; p < GP_SPLIT; ++p) s += Gp[(size_t)p * 102400 + idx];
    if ((idx / 320) == (idx % 320)) s += 1e-6f;
    G[idx] = s;
}

// ============ fused Jacobi solve: G X = Y, 10 iters in one launch ============
__global__ __launch_bounds__(256) void k_solve(const float* __restrict__ G, const float* __restrict__ Y,
                                               float* __restrict__ X) {
    __shared__ float Xl[NSEN * 8];
    const int c0 = blockIdx.x * 8;
    const int tid = threadIdx.x;
    const int i1 = tid, i2 = 256 + tid;
    const bool has2 = i2 < NSEN;
    const int i2c = has2 ? i2 : 0;

    float y1[8], y2[8], x1[8], x2[8];
    const float d1i = 1.f / G[i1 * 320 + i1];
    const float d2i = has2 ? (1.f / G[i2c * 320 + i2c]) : 0.f;
    *(float4*)&y1[0] = *(const float4*)&Y[i1 * NT + c0];
    *(float4*)&y1[4] = *(const float4*)&Y[i1 * NT + c0 + 4];
    *(float4*)&y2[0] = *(const float4*)&Y[i2c * NT + c0];
    *(float4*)&y2[4] = *(const float4*)&Y[i2c * NT + c0 + 4];
    #pragma unroll
    for (int c = 0; c < 8; ++c) { x1[c] = y1[c] * d1i; x2[c] = y2[c] * d2i; }
    #pragma unroll
    for (int c = 0; c < 8; ++c) { Xl[i1 * 8 + c] = x1[c]; if (has2) Xl[i2 * 8 + c] = x2[c]; }
    __syncthreads();

    for (int it = 0; it < JITERS; ++it) {
        float r1[8], r2[8];
        #pragma unroll
        for (int c = 0; c < 8; ++c) { r1[c] = y1[c]; r2[c] = y2[c]; }
        for (int k = 0; k < NSEN; ++k) {
            const float g1 = G[k * 320 + i1];      // symmetric: G[i][k] == G[k][i], coalesced
            const float g2 = G[k * 320 + i2c];
            const float4 xa = *(const float4*)&Xl[k * 8];
            const float4 xb = *(const float4*)&Xl[k * 8 + 4];
            r1[0] = fmaf(-g1, xa.x, r1[0]); r1[1] = fmaf(-g1, xa.y, r1[1]);
            r1[2] = fmaf(-g1, xa.z, r1[2]); r1[3] = fmaf(-g1, xa.w, r1[3]);
            r1[4] = fmaf(-g1, xb.x, r1[4]); r1[5] = fmaf(-g1, xb.y, r1[5]);
            r1[6] = fmaf(-g1, xb.z, r1[6]); r1[7] = fmaf(-g1, xb.w, r1[7]);
            r2[0] = fmaf(-g2, xa.x, r2[0]); r2[1] = fmaf(-g2, xa.y, r2[1]);
            r2[2] = fmaf(-g2, xa.z, r2[2]); r2[3] = fmaf(-g2, xa.w, r2[3]);
            r2[4] = fmaf(-g2, xb.x, r2[4]); r2[5] = fmaf(-g2, xb.y, r2[5]);
            r2[6] = fmaf(-g2, xb.z, r2[6]); r2[7] = fmaf(-g2, xb.w, r2[7]);
        }
        __syncthreads();
        #pragma unroll
        for (int c = 0; c < 8; ++c) {
            x1[c] += r1[c] * d1i; x2[c] += r2[c] * d2i;
            Xl[i1 * 8 + c] = x1[c];
            if (has2) Xl[i2 * 8 + c] = x2[c];
        }
        __syncthreads();
    }
    *(float4*)&X[i1 * NT + c0] = *(const float4*)&x1[0];
    *(float4*)&X[i1 * NT + c0 + 4] = *(const float4*)&x1[4];
    if (has2) {
        *(float4*)&X[i2 * NT + c0] = *(const float4*)&x2[0];
        *(float4*)&X[i2 * NT + c0 + 4] = *(const float4*)&x2[4];
    }
}

// ============ Zt[h][s] = (X * W_in[:, :256]^T)^T in bf16 (stride 352) ============
__global__ __launch_bounds__(128) void k_Z(const float* __restrict__ X, const float* __restrict__ W_in,
                                           short* __restrict__ Zt) {
    __shared__ float xs[NT];
    const int i = blockIdx.x, h = threadIdx.x;
    xs[h] = X[i * NT + h];
    xs[h + 128] = X[i * NT + h + 128];
    __syncthreads();
    const float* w = W_in + (size_t)h * (NT + NF);
    float acc = 0.f;
    #pragma unroll 4
    for (int t = 0; t < NT; ++t) acc = fmaf(xs[t], w[t], acc);
    Zt[h * 352 + i] = f2b(acc);
}

// ============ prep: WtL (3x[h][256] = [Ws^T|Wm^T]), Wob, Zt wf columns ============
__global__ void k_prep(const float* __restrict__ W_self, const float* __restrict__ W_msg,
                       const float* __restrict__ W_out, const float* __restrict__ W_in,
                       short* __restrict__ WtL, short* __restrict__ Wob, short* __restrict__ Zt) {
    const int idx = blockIdx.x * 256 + threadIdx.x;
    if (idx < 3 * 128 * 256) {
        const int l = idx >> 15, rem = idx & 32767;
        const int h = rem >> 8, k = rem & 255;
        float v = (k < 128) ? W_self[l * 16384 + k * 128 + h] : W_msg[l * 16384 + (k - 128) * 128 + h];
        WtL[idx] = f2b(v);
    } else if (idx < 3 * 128 * 256 + 256 * 128) {
        const int j = idx - 3 * 128 * 256;
        Wob[j] = f2b(W_out[j]);
    } else if (idx < 3 * 128 * 256 + 256 * 128 + 128 * 8) {
        const int j = idx - (3 * 128 * 256 + 256 * 128);
        const int h = j >> 3, f = j & 7;
        Zt[h * 352 + 320 + f] = f2b(W_in[(size_t)h * (NT + NF) + NT + f]);
    }
}

// ============ x0 = L^T Z + vf*wf^T + b_in (MFMA; vf folded in as K=320..327) ============
__global__ __launch_bounds__(256) void k_x0(const float* __restrict__ L, const short* __restrict__ Zt,
                                            const float* __restrict__ vf, const float* __restrict__ b_in,
                                            short* __restrict__ xout) {
    __shared__ short At[128 * 40];
    __shared__ short Bt[128 * 40];
    __shared__ float bs[128];
    const int n0 = blockIdx.x * 128;
    const int tid = threadIdx.x;
    const int lane = tid & 63, wid = tid >> 6;
    const int wr = wid >> 1, wc = wid & 1;
    if (tid < 128) bs[tid] = b_in[tid];

    f32x4 acc[4][4] = {};

    for (int s0 = 0; s0 <= 320; s0 += 32) {
        __syncthreads();
        {   // A stage: At[n][s] = L[s][n] (transposed) or vf fold (s0==320)
            const int s_loc = tid >> 3, nseg = (tid & 7) * 16;
            float v[16];
            if (s0 < 320) {
                const int srow = s0 + s_loc;
                const bool okrow = srow < NSEN;
                const float* src = L + (size_t)srow * NSRC + n0 + nseg;
                #pragma unroll
                for (int i = 0; i < 16; i += 4) {
                    float4 f = make_float4(0.f, 0.f, 0.f, 0.f);
                    const int gn = n0 + nseg + i;
                    if (okrow) {
                        if (gn + 3 < NSRC) f = *(const float4*)(src + i);
                        else {
                            if (gn < NSRC) f.x = src[i];
                            if (gn + 1 < NSRC) f.y = src[i + 1];
                            if (gn + 2 < NSRC) f.z = src[i + 2];
                        }
                    }
                    v[i] = f.x; v[i + 1] = f.y; v[i + 2] = f.z; v[i + 3] = f.w;
                }
            } else {
                #pragma unroll
                for (int i = 0; i < 16; ++i) {
                    const int gn = n0 + nseg + i;
                    v[i] = (s_loc < NF && gn < NSRC) ? vf[(size_t)gn * NF + s_loc] : 0.f;
                }
            }
            #pragma unroll
            for (int i = 0; i < 16; ++i) At[(nseg + i) * 40 + s_loc] = f2b(v[i]);
        }
        {   // B stage: Bt[h][0..31] = Zt[h][s0..s0+31]
            const int h = tid >> 1, seg = tid & 1;
            const short8 z0 = *(const short8*)&Zt[h * 352 + s0 + seg * 16];
            const short8 z1 = *(const short8*)&Zt[h * 352 + s0 + seg * 16 + 8];
            *(short8*)&Bt[h * 40 + seg * 16] = z0;
            *(short8*)&Bt[h * 40 + seg * 16 + 8] = z1;
        }
        __syncthreads();
        const int kb = (lane >> 4) * 8;
        short8 a[4], b[4];
        #pragma unroll
        for (int i = 0; i < 4; ++i) a[i] = *(const short8*)&At[(wr * 64 + i * 16 + (lane & 15)) * 40 + kb];
        #pragma unroll
        for (int j = 0; j < 4; ++j) b[j] = *(const short8*)&Bt[(wc * 64 + j * 16 + (lane & 15)) * 40 + kb];
        #pragma unroll
        for (int i = 0; i < 4; ++i)
            #pragma unroll
            for (int j = 0; j < 4; ++j)
                acc[i][j] = __builtin_amdgcn_mfma_f32_16x16x32_bf16(a[i], b[j], acc[i][j], 0, 0, 0);
    }
    #pragma unroll
    for (int i = 0; i < 4; ++i)
        #pragma unroll
        for (int j = 0; j < 4; ++j) {
            const int h = wc * 64 + j * 16 + (lane & 15);
            #pragma unroll
            for (int rr = 0; rr < 4; ++rr) {
                const int n = n0 + wr * 64 + i * 16 + (lane >> 4) * 4 + rr;
                if (n < NSRC) xout[(size_t)n * NH + h] = f2b(acc[i][j][rr] + bs[h]);
            }
        }
}

// ============ CSR build ============
__global__ void k_hist(const int* __restrict__ recv, int* __restrict__ cnt) {
    int e = blockIdx.x * 256 + threadIdx.x;
    if (e < NE) atomicAdd(&cnt[recv[e]], 1);
}

__global__ __launch_bounds__(1024) void k_scan(const int* __restrict__ cnt, int* __restrict__ rowptr) {
    __shared__ int sd[1024];
    const int tid = threadIdx.x;
    int running = 0;
    for (int base = 0; base < NSRC; base += 8192) {
        int off = base + tid * 8;
        int v[8]; int s = 0;
        #pragma unroll
        for (int j = 0; j < 8; ++j) { v[j] = (off + j < NSRC) ? cnt[off + j] : 0; s += v[j]; }
        __syncthreads();
        sd[tid] = s;
        __syncthreads();
        for (int d = 1; d < 1024; d <<= 1) {
            int add = (tid >= d) ? sd[tid - d] : 0;
            __syncthreads();
            sd[tid] += add;
            __syncthreads();
        }
        int run = running + sd[tid] - s;
        int total = sd[1023];
        #pragma unroll
        for (int j = 0; j < 8; ++j) { if (off + j < NSRC) rowptr[off + j] = run; run += v[j]; }
        running += total;
    }
    if (tid == 0) rowptr[NSRC] = running;
}

__global__ void k_fill(const int* __restrict__ send, const int* __restrict__ recv,
                       int* __restrict__ cursor, int* __restrict__ csr) {
    int e = blockIdx.x * 256 + threadIdx.x;
    if (e < NE) {
        int pos = atomicAdd(&cursor[recv[e]], 1);
        csr[pos] = send[e];
    }
}

// ============ mean aggregation over bf16 activations (pull, 1 wave / node) ============
__global__ __launch_bounds__(256) void k_agg(const short* __restrict__ x, const int* __restrict__ rowptr,
                                             const int* __restrict__ csr, short* __restrict__ mean) {
    const int lane = threadIdx.x & 63;
    const int n = blockIdx.x * 4 + (threadIdx.x >> 6);
    if (n >= NSRC) return;
    const int beg = rowptr[n], end = rowptr[n + 1];
    float a0 = 0.f, a1 = 0.f;
    for (int e = beg; e < end; ++e) {
        const int s = csr[e];
        const unsigned u = *(const unsigned*)&x[(size_t)s * NH + lane * 2];
        a0 += b2f((unsigned short)(u & 0xffff));
        a1 += b2f((unsigned short)(u >> 16));
    }
    const int d = end - beg;
    const float inv = 1.f / (float)(d > 0 ? d : 1);
    const unsigned o = (unsigned)(unsigned short)f2b(a0 * inv) | ((unsigned)(unsigned short)f2b(a1 * inv) << 16);
    *(unsigned*)&mean[(size_t)n * NH + lane * 2] = o;
}

// ============ GCN layer: out = relu(x*Ws + mean*Wm + b), bf16 MFMA, K=256 ============
__global__ __launch_bounds__(256) void k_gcn(const short* __restrict__ x, const short* __restrict__ mean,
                                             const short* __restrict__ Wt, const float* __restrict__ b,
                                             short* __restrict__ out) {
    __shared__ short At[128 * 40];
    __shared__ short Bt[128 * 40];
    __shared__ float bs[128];
    const int n0 = blockIdx.x * 128;
    const int tid = threadIdx.x;
    const int lane = tid & 63, wid = tid >> 6;
    const int wr = wid >> 1, wc = wid & 1;
    if (tid < 128) bs[tid] = b[tid];

    f32x4 acc[4][4] = {};

    for (int kc = 0; kc < 8; ++kc) {
        const short* Asrc = (kc < 4) ? x : mean;
        const int ko = (kc & 3) * 32;
        __syncthreads();
        {
            const int nl = tid >> 1, seg = tid & 1;
            const int gn = n0 + nl;
            short8 v0 = {0,0,0,0,0,0,0,0}, v1 = {0,0,0,0,0,0,0,0};
            if (gn < NSRC) {
                v0 = *(const short8*)&Asrc[(size_t)gn * NH + ko + seg * 16];
                v1 = *(const short8*)&Asrc[(size_t)gn * NH + ko + seg * 16 + 8];
            }
            *(short8*)&At[nl * 40 + seg * 16] = v0;
            *(short8*)&At[nl * 40 + seg * 16 + 8] = v1;
        }
        {
            const int h = tid >> 1, seg = tid & 1;
            const short8 w0 = *(const short8*)&Wt[h * 256 + kc * 32 + seg * 16];
            const short8 w1 = *(const short8*)&Wt[h * 256 + kc * 32 + seg * 16 + 8];
            *(short8*)&Bt[h * 40 + seg * 16] = w0;
            *(short8*)&Bt[h * 40 + seg * 16 + 8] = w1;
        }
        __syncthreads();
        const int kb = (lane >> 4) * 8;
        short8 a[4], bb[4];
        #pragma unroll
        for (int i = 0; i < 4; ++i) a[i] = *(const short8*)&At[(wr * 64 + i * 16 + (lane & 15)) * 40 + kb];
        #pragma unroll
        for (int j = 0; j < 4; ++j) bb[j] = *(const short8*)&Bt[(wc * 64 + j * 16 + (lane & 15)) * 40 + kb];
        #pragma unroll
        for (int i = 0; i < 4; ++i)
            #pragma unroll
            for (int j = 0; j < 4; ++j)
                acc[i][j] = __builtin_amdgcn_mfma_f32_16x16x32_bf16(a[i], bb[j], acc[i][j], 0, 0, 0);
    }
    #pragma unroll
    for (int i = 0; i < 4; ++i)
        #pragma unroll
        for (int j = 0; j < 4; ++j) {
            const int h = wc * 64 + j * 16 + (lane & 15);
            #pragma unroll
            for (int rr = 0; rr < 4; ++rr) {
                const int n = n0 + wr * 64 + i * 16 + (lane >> 4) * 4 + rr;
                if (n < NSRC) out[(size_t)n * NH + h] = f2b(fmaxf(acc[i][j][rr] + bs[h], 0.f));
            }
        }
}

// ============ J = x * W_out^T + b_out (bf16 MFMA, fp32 out) ============
__global__ __launch_bounds__(256) void k_out(const short* __restrict__ x, const short* __restrict__ Wob,
                                             const float* __restrict__ bout, float* __restrict__ J) {
    __shared__ short At[128 * 40];
    __shared__ short Bt[128 * 40];
    __shared__ float bs[128];
    const int n0 = blockIdx.x * 128;
    const int t0 = blockIdx.y * 128;
    const int tid = threadIdx.x;
    const int lane = tid & 63, wid = tid >> 6;
    const int wr = wid >> 1, wc = wid & 1;
    if (tid < 128) bs[tid] = bout[t0 + tid];

    f32x4 acc[4][4] = {};

    for (int kc = 0; kc < 4; ++kc) {
        __syncthreads();
        {
            const int nl = tid >> 1, seg = tid & 1;
            const int gn = n0 + nl;
            short8 v0 = {0,0,0,0,0,0,0,0}, v1 = {0,0,0,0,0,0,0,0};
            if (gn < NSRC) {
                v0 = *(const short8*)&x[(size_t)gn * NH + kc * 32 + seg * 16];
                v1 = *(const short8*)&x[(size_t)gn * NH + kc * 32 + seg * 16 + 8];
            }
            *(short8*)&At[nl * 40 + seg * 16] = v0;
            *(short8*)&At[nl * 40 + seg * 16 + 8] = v1;
        }
        {
            const int tl = tid >> 1, seg = tid & 1;
            const short8 w0 = *(const short8*)&Wob[(t0 + tl) * NH + kc * 32 + seg * 16];
            const short8 w1 = *(const short8*)&Wob[(t0 + tl) * NH + kc * 32 + seg * 16 + 8];
            *(short8*)&Bt[tl * 40 + seg * 16] = w0;
            *(short8*)&Bt[tl * 40 + seg * 16 + 8] = w1;
        }
        __syncthreads();
        const int kb = (lane >> 4) * 8;
        short8 a[4], bb[4];
        #pragma unroll
        for (int i = 0; i < 4; ++i) a[i] = *(const short8*)&At[(wr * 64 + i * 16 + (lane & 15)) * 40 + kb];
        #pragma unroll
        for (int j = 0; j < 4; ++j) bb[j] = *(const short8*)&Bt[(wc * 64 + j * 16 + (lane & 15)) * 40 + kb];
        #pragma unroll
        for (int i = 0; i < 4; ++i)
            #pragma unroll
            for (int j = 0; j < 4; ++j)
                acc[i][j] = __builtin_amdgcn_mfma_f32_16x16x32_bf16(a[i], bb[j], acc[i][j], 0, 0, 0);
    }
    #pragma unroll
    for (int i = 0; i < 4; ++i)
        #pragma unroll
        for (int j = 0; j < 4; ++j) {
            const int tl = wc * 64 + j * 16 + (lane & 15);   // block-local time index
            const int t = t0 + tl;
            #pragma unroll
            for (int rr = 0; rr < 4; ++rr) {
                const int n = n0 + wr * 64 + i * 16 + (lane >> 4) * 4 + rr;
                if (n < NSRC) J[(size_t)n * NT + t] = acc[i][j][rr] + bs[tl];  // FIX: bs[tl], not bs[t]
            }
        }
}

extern "C" void kernel_launch(void* const* d_in, const int* in_sizes, int n_in,
                              void* d_out, int out_size, void* d_ws, size_t ws_size,
                              hipStream_t stream) {
    const float* Y      = (const float*)d_in[0];
    const float* L      = (const float*)d_in[1];
    const float* vf     = (const float*)d_in[2];
    const int*   send   = (const int*)d_in[3];
    const int*   recv   = (const int*)d_in[4];
    const float* W_in   = (const float*)d_in[5];
    const float* b_in   = (const float*)d_in[6];
    const float* W_self = (const float*)d_in[7];
    const float* W_msg  = (const float*)d_in[8];
    const float* b_lay  = (const float*)d_in[9];
    const float* W_out  = (const float*)d_in[10];
    const float* b_out  = (const float*)d_in[11];
    float* out = (float*)d_out;

    char* ws = (char*)d_ws;
    size_t off = 0;
    auto alloc = [&](size_t bytes) -> void* {
        void* p = ws + off;
        off += (bytes + 255) & ~(size_t)255;
        return p;
    };
    // big region: Gp (125*320*320*4 = 51.2MB) reused later as xA+xB (2*100000*128*2 = 51.2MB)
    char* big    = (char*)alloc((size_t)GP_SPLIT * 320 * 320 * 4);
    float* Gp    = (float*)big;
    short* xA    = (short*)big;
    short* xB    = (short*)(big + (size_t)NSRC * NH * 2);
    float* G     = (float*)alloc((size_t)320 * 320 * 4);
    float* X     = (float*)alloc((size_t)NSEN * NT * 4);
    short* Zt    = (short*)alloc((size_t)NH * 352 * 2);
    short* WtL   = (short*)alloc((size_t)NL * NH * 256 * 2);
    short* Wob   = (short*)alloc((size_t)NT * NH * 2);
    int* rowptr  = (int*)alloc((size_t)(NSRC + 1) * 4);
    int* cursor  = (int*)alloc((size_t)NSRC * 4);
    int* cnt     = (int*)alloc((size_t)NSRC * 4);
    int* csr     = (int*)alloc((size_t)NE * 4);

    hipMemsetAsync(cnt, 0, (size_t)NSRC * 4, stream);
    hipMemsetAsync(Zt, 0, (size_t)NH * 352 * 2, stream);

    k_prep<<<(3 * 128 * 256 + 256 * 128 + 128 * 8 + 255) / 256, 256, 0, stream>>>(
        W_self, W_msg, W_out, W_in, WtL, Wob, Zt);

    k_hist<<<(NE + 255) / 256, 256, 0, stream>>>(recv, cnt);
    k_scan<<<1, 1024, 0, stream>>>(cnt, rowptr);
    hipMemcpyAsync(cursor, rowptr, (size_t)NSRC * 4, hipMemcpyDeviceToDevice, stream);
    k_fill<<<(NE + 255) / 256, 256, 0, stream>>>(send, recv, cursor, csr);

    k_gram_p1<<<256, 512, 0, stream>>>(L, Gp);
    k_gram_p2<<<(320 * 320 + 255) / 256, 256, 0, stream>>>(Gp, G);
    k_solve<<<NT / 8, 256, 0, stream>>>(G, Y, X);
    k_Z<<<NSEN, 128, 0, stream>>>(X, W_in, Zt);
    k_x0<<<(NSRC + 127) / 128, 256, 0, stream>>>(L, Zt, vf, b_in, xA);   // overwrites Gp (dead)

    short* x = xA;
    short* m = xB;
    for (int l = 0; l < NL; ++l) {
        k_agg<<<(NSRC + 3) / 4, 256, 0, stream>>>(x, rowptr, csr, m);
        k_gcn<<<(NSRC + 127) / 128, 256, 0, stream>>>(
            x, m, WtL + (size_t)l * NH * 256, b_lay + (size_t)l * NH, m);
        short* t = x; x = m; m = t;
    }
    k_out<<<dim3((NSRC + 127) / 128, 2), 256, 0, stream>>>(x, Wob, b_out, out);
}

// Round 5
// 867.998 us; speedup vs baseline: 2.4132x; 1.1012x over previous
//
#include <hip/hip_runtime.h>

#define NSRC 100000
#define NSEN 306
#define NT 256
#define NF 8
#define NH 128
#define NL 3
#define NE 600000
#define JITERS 6

#define GP_SPLIT 125
#define GP_CHUNK 800   // 125*800 = 100000 exactly

typedef short short8 __attribute__((ext_vector_type(8)));
typedef float f32x4 __attribute__((ext_vector_type(4)));

__device__ __forceinline__ short f2b(float f) {
    union { float f; unsigned u; } v; v.f = f;
    unsigned r = v.u + 0x7fffu + ((v.u >> 16) & 1u);
    return (short)(r >> 16);
}
__device__ __forceinline__ float b2f(unsigned short s) {
    union { unsigned u; float f; } v; v.u = ((unsigned)s) << 16;
    return v.f;
}

// ============ gram phase 1: Gp[p] = L[:,chunk_p] * L[:,chunk_p]^T (bf16 MFMA) ============
__global__ __launch_bounds__(512) void k_gram_p1(const float* __restrict__ L, float* __restrict__ Gp) {
    __shared__ short T[320 * 72];  // rows 0..319 of L (bf16), 64 k-cols, pad stride 72
    const int bid = blockIdx.x;
    const int g = bid >> 4, r = bid & 15;
    const int p = g * 8 + (r & 7);          // k-chunk index
    if (p >= GP_SPLIT) return;
    const int bi = r >> 3;                  // row half: 0 or 1
    const int c0 = p * GP_CHUNK;
    const int cend = c0 + GP_CHUNK;
    const int tid = threadIdx.x;
    const int lane = tid & 63, wid = tid >> 6;
    const int wr = wid >> 2, wc = wid & 3;  // 2x4 waves, each 80x80

    f32x4 acc[5][5] = {};

    for (int s0 = c0; s0 < cend; s0 += 64) {
        __syncthreads();
        for (int task = tid; task < 640; task += 512) {
            const int row = task >> 1, half = task & 1;
            const int col = s0 + half * 32;
            const bool ok = (row < NSEN) && (col + 31 < cend);
            const float* src = L + (size_t)row * NSRC + col;
            #pragma unroll
            for (int q = 0; q < 4; ++q) {
                float4 f0 = make_float4(0.f, 0.f, 0.f, 0.f);
                float4 f1 = make_float4(0.f, 0.f, 0.f, 0.f);
                if (ok) { f0 = *(const float4*)(src + q * 8); f1 = *(const float4*)(src + q * 8 + 4); }
                short8 t;
                t[0] = f2b(f0.x); t[1] = f2b(f0.y); t[2] = f2b(f0.z); t[3] = f2b(f0.w);
                t[4] = f2b(f1.x); t[5] = f2b(f1.y); t[6] = f2b(f1.z); t[7] = f2b(f1.w);
                *(short8*)&T[row * 72 + half * 32 + q * 8] = t;
            }
        }
        __syncthreads();
        #pragma unroll
        for (int ks = 0; ks < 2; ++ks) {
            const int kb = ks * 32 + (lane >> 4) * 8;
            short8 a[5], b[5];
            #pragma unroll
            for (int i = 0; i < 5; ++i) {
                a[i] = *(const short8*)&T[(bi * 160 + wr * 80 + i * 16 + (lane & 15)) * 72 + kb];
                b[i] = *(const short8*)&T[(wc * 80 + i * 16 + (lane & 15)) * 72 + kb];
            }
            #pragma unroll
            for (int i = 0; i < 5; ++i)
                #pragma unroll
                for (int j = 0; j < 5; ++j)
                    acc[i][j] = __builtin_amdgcn_mfma_f32_16x16x32_bf16(a[i], b[j], acc[i][j], 0, 0, 0);
        }
    }
    float* dst = Gp + (size_t)p * 320 * 320;
    #pragma unroll
    for (int i = 0; i < 5; ++i)
        #pragma unroll
        for (int j = 0; j < 5; ++j) {
            const int gj = wc * 80 + j * 16 + (lane & 15);
            #pragma unroll
            for (int rr = 0; rr < 4; ++rr) {
                const int gi = bi * 160 + wr * 80 + i * 16 + (lane >> 4) * 4 + rr;
                dst[gi * 320 + gj] = acc[i][j][rr];
            }
        }
}

// ============ gram phase 2: G = sum_p Gp[p], + reg^2 on diag ============
__global__ void k_gram_p2(const float* __restrict__ Gp, float* __restrict__ G) {
    const int idx = blockIdx.x * 256 + threadIdx.x;
    if (idx >= 320 * 320) return;
    float s = 0.f;
    for (int p = 0; p < GP_SPLIT; ++p) s += Gp[(size_t)p * 102400 + idx];
    if ((idx / 320) == (idx % 320)) s += 1e-6f;
    G[idx] = s;
}

// ============ Yw = Y * W_in[:, :256]^T  (306 x 128, fp32) ============
__global__ __launch_bounds__(128) void k_Yw(const float* __restrict__ Y, const float* __restrict__ W_in,
                                            float* __restrict__ Yw) {
    __shared__ float ys[NT];
    const int i = blockIdx.x, h = threadIdx.x;
    ys[h] = Y[i * NT + h];
    ys[h + 128] = Y[i * NT + h + 128];
    __syncthreads();
    const float* w = W_in + (size_t)h * (NT + NF);
    float acc = 0.f;
    #pragma unroll 4
    for (int t = 0; t < NT; ++t) acc = fmaf(ys[t], w[t], acc);
    Yw[i * 128 + h] = acc;
}

// ===== fused Jacobi solve in Z-space: G Z = Yw (306x128), 6 iters, writes Zt bf16 =====
// 64 blocks x 2 cols. k-loop padded to 320 (G rows/cols 306..319 are exactly zero).
__global__ __launch_bounds__(256) void k_solve(const float* __restrict__ G, const float* __restrict__ Yw,
                                               short* __restrict__ Zt) {
    __shared__ float Xl[320 * 2];
    const int c0 = blockIdx.x * 2;
    const int tid = threadIdx.x;
    const int i1 = tid;
    const int i2 = 256 + tid;
    const bool has2 = i2 < NSEN;
    const int i2c = has2 ? i2 : 0;

    const float d1i = 1.f / G[i1 * 320 + i1];
    const float d2i = has2 ? (1.f / G[i2c * 320 + i2c]) : 0.f;
    float y1[2], y2[2], x1[2], x2[2];
    y1[0] = Yw[i1 * 128 + c0]; y1[1] = Yw[i1 * 128 + c0 + 1];
    y2[0] = has2 ? Yw[i2 * 128 + c0] : 0.f;
    y2[1] = has2 ? Yw[i2 * 128 + c0 + 1] : 0.f;
    x1[0] = y1[0] * d1i; x1[1] = y1[1] * d1i;
    x2[0] = y2[0] * d2i; x2[1] = y2[1] * d2i;
    Xl[i1 * 2] = x1[0]; Xl[i1 * 2 + 1] = x1[1];
    if (has2)      { Xl[i2 * 2] = x2[0]; Xl[i2 * 2 + 1] = x2[1]; }
    else if (tid < 64) { Xl[i2 * 2] = 0.f; Xl[i2 * 2 + 1] = 0.f; }  // zero rows 306..319
    __syncthreads();

    for (int it = 0; it < JITERS; ++it) {
        float r1[2] = {y1[0], y1[1]};
        float r2[2] = {y2[0], y2[1]};
        for (int k0 = 0; k0 < 320; k0 += 8) {
            float g1[8], g2[8];
            float2 xx[8];
            #pragma unroll
            for (int u = 0; u < 8; ++u) {
                g1[u] = G[(k0 + u) * 320 + i1];
                g2[u] = G[(k0 + u) * 320 + i2c];
                xx[u] = *(const float2*)&Xl[(k0 + u) * 2];
            }
            #pragma unroll
            for (int u = 0; u < 8; ++u) {
                r1[0] = fmaf(-g1[u], xx[u].x, r1[0]);
                r1[1] = fmaf(-g1[u], xx[u].y, r1[1]);
                r2[0] = fmaf(-g2[u], xx[u].x, r2[0]);
                r2[1] = fmaf(-g2[u], xx[u].y, r2[1]);
            }
        }
        __syncthreads();
        x1[0] += r1[0] * d1i; x1[1] += r1[1] * d1i;
        x2[0] += r2[0] * d2i; x2[1] += r2[1] * d2i;
        Xl[i1 * 2] = x1[0]; Xl[i1 * 2 + 1] = x1[1];
        if (has2) { Xl[i2 * 2] = x2[0]; Xl[i2 * 2 + 1] = x2[1]; }
        __syncthreads();
    }
    // epilogue: Zt[h][s] = Z[s][h], bf16, stride 352
    Zt[(c0) * 352 + i1]     = f2b(x1[0]);
    Zt[(c0 + 1) * 352 + i1] = f2b(x1[1]);
    if (has2) {
        Zt[(c0) * 352 + i2]     = f2b(x2[0]);
        Zt[(c0 + 1) * 352 + i2] = f2b(x2[1]);
    }
}

// ============ prep: WtL (3x[h][256] = [Ws^T|Wm^T]), Wob, Zt wf columns ============
__global__ void k_prep(const float* __restrict__ W_self, const float* __restrict__ W_msg,
                       const float* __restrict__ W_out, const float* __restrict__ W_in,
                       short* __restrict__ WtL, short* __restrict__ Wob, short* __restrict__ Zt) {
    const int idx = blockIdx.x * 256 + threadIdx.x;
    if (idx < 3 * 128 * 256) {
        const int l = idx >> 15, rem = idx & 32767;
        const int h = rem >> 8, k = rem & 255;
        float v = (k < 128) ? W_self[l * 16384 + k * 128 + h] : W_msg[l * 16384 + (k - 128) * 128 + h];
        WtL[idx] = f2b(v);
    } else if (idx < 3 * 128 * 256 + 256 * 128) {
        const int j = idx - 3 * 128 * 256;
        Wob[j] = f2b(W_out[j]);
    } else if (idx < 3 * 128 * 256 + 256 * 128 + 128 * 8) {
        const int j = idx - (3 * 128 * 256 + 256 * 128);
        const int h = j >> 3, f = j & 7;
        Zt[h * 352 + 320 + f] = f2b(W_in[(size_t)h * (NT + NF) + NT + f]);
    }
}

// ============ x0 = L^T Z + vf*wf^T + b_in (MFMA; vf folded in as K=320..327) ============
__global__ __launch_bounds__(256) void k_x0(const float* __restrict__ L, const short* __restrict__ Zt,
                                            const float* __restrict__ vf, const float* __restrict__ b_in,
                                            short* __restrict__ xout) {
    __shared__ short At[128 * 40];
    __shared__ short Bt[128 * 40];
    __shared__ float bs[128];
    const int n0 = blockIdx.x * 128;
    const int tid = threadIdx.x;
    const int lane = tid & 63, wid = tid >> 6;
    const int wr = wid >> 1, wc = wid & 1;
    if (tid < 128) bs[tid] = b_in[tid];

    f32x4 acc[4][4] = {};

    for (int s0 = 0; s0 <= 320; s0 += 32) {
        __syncthreads();
        {   // A stage: At[n][s] = L[s][n] (transposed) or vf fold (s0==320)
            const int s_loc = tid >> 3, nseg = (tid & 7) * 16;
            float v[16];
            if (s0 < 320) {
                const int srow = s0 + s_loc;
                const bool okrow = srow < NSEN;
                const float* src = L + (size_t)srow * NSRC + n0 + nseg;
                #pragma unroll
                for (int i = 0; i < 16; i += 4) {
                    float4 f = make_float4(0.f, 0.f, 0.f, 0.f);
                    const int gn = n0 + nseg + i;
                    if (okrow) {
                        if (gn + 3 < NSRC) f = *(const float4*)(src + i);
                        else {
                            if (gn < NSRC) f.x = src[i];
                            if (gn + 1 < NSRC) f.y = src[i + 1];
                            if (gn + 2 < NSRC) f.z = src[i + 2];
                        }
                    }
                    v[i] = f.x; v[i + 1] = f.y; v[i + 2] = f.z; v[i + 3] = f.w;
                }
            } else {
                #pragma unroll
                for (int i = 0; i < 16; ++i) {
                    const int gn = n0 + nseg + i;
                    v[i] = (s_loc < NF && gn < NSRC) ? vf[(size_t)gn * NF + s_loc] : 0.f;
                }
            }
            #pragma unroll
            for (int i = 0; i < 16; ++i) At[(nseg + i) * 40 + s_loc] = f2b(v[i]);
        }
        {   // B stage: Bt[h][0..31] = Zt[h][s0..s0+31]
            const int h = tid >> 1, seg = tid & 1;
            const short8 z0 = *(const short8*)&Zt[h * 352 + s0 + seg * 16];
            const short8 z1 = *(const short8*)&Zt[h * 352 + s0 + seg * 16 + 8];
            *(short8*)&Bt[h * 40 + seg * 16] = z0;
            *(short8*)&Bt[h * 40 + seg * 16 + 8] = z1;
        }
        __syncthreads();
        const int kb = (lane >> 4) * 8;
        short8 a[4], b[4];
        #pragma unroll
        for (int i = 0; i < 4; ++i) a[i] = *(const short8*)&At[(wr * 64 + i * 16 + (lane & 15)) * 40 + kb];
        #pragma unroll
        for (int j = 0; j < 4; ++j) b[j] = *(const short8*)&Bt[(wc * 64 + j * 16 + (lane & 15)) * 40 + kb];
        #pragma unroll
        for (int i = 0; i < 4; ++i)
            #pragma unroll
            for (int j = 0; j < 4; ++j)
                acc[i][j] = __builtin_amdgcn_mfma_f32_16x16x32_bf16(a[i], b[j], acc[i][j], 0, 0, 0);
    }
    #pragma unroll
    for (int i = 0; i < 4; ++i)
        #pragma unroll
        for (int j = 0; j < 4; ++j) {
            const int h = wc * 64 + j * 16 + (lane & 15);
            #pragma unroll
            for (int rr = 0; rr < 4; ++rr) {
                const int n = n0 + wr * 64 + i * 16 + (lane >> 4) * 4 + rr;
                if (n < NSRC) xout[(size_t)n * NH + h] = f2b(acc[i][j][rr] + bs[h]);
            }
        }
}

// ============ CSR build ============
__global__ void k_hist(const int* __restrict__ recv, int* __restrict__ cnt) {
    int e = blockIdx.x * 256 + threadIdx.x;
    if (e < NE) atomicAdd(&cnt[recv[e]], 1);
}

__global__ __launch_bounds__(1024) void k_scan(const int* __restrict__ cnt, int* __restrict__ rowptr) {
    __shared__ int sd[1024];
    const int tid = threadIdx.x;
    int running = 0;
    for (int base = 0; base < NSRC; base += 8192) {
        int off = base + tid * 8;
        int v[8]; int s = 0;
        #pragma unroll
        for (int j = 0; j < 8; ++j) { v[j] = (off + j < NSRC) ? cnt[off + j] : 0; s += v[j]; }
        __syncthreads();
        sd[tid] = s;
        __syncthreads();
        for (int d = 1; d < 1024; d <<= 1) {
            int add = (tid >= d) ? sd[tid - d] : 0;
            __syncthreads();
            sd[tid] += add;
            __syncthreads();
        }
        int run = running + sd[tid] - s;
        int total = sd[1023];
        #pragma unroll
        for (int j = 0; j < 8; ++j) { if (off + j < NSRC) rowptr[off + j] = run; run += v[j]; }
        running += total;
    }
    if (tid == 0) rowptr[NSRC] = running;
}

__global__ void k_fill(const int* __restrict__ send, const int* __restrict__ recv,
                       int* __restrict__ cursor, int* __restrict__ csr) {
    int e = blockIdx.x * 256 + threadIdx.x;
    if (e < NE) {
        int pos = atomicAdd(&cursor[recv[e]], 1);
        csr[pos] = send[e];
    }
}

// ============ mean aggregation over bf16 activations (pull, 1 wave / node) ============
__global__ __launch_bounds__(256) void k_agg(const short* __restrict__ x, const int* __restrict__ rowptr,
                                             const int* __restrict__ csr, short* __restrict__ mean) {
    const int lane = threadIdx.x & 63;
    const int n = blockIdx.x * 4 + (threadIdx.x >> 6);
    if (n >= NSRC) return;
    const int beg = rowptr[n], end = rowptr[n + 1];
    float a0 = 0.f, a1 = 0.f;
    for (int e = beg; e < end; ++e) {
        const int s = csr[e];
        const unsigned u = *(const unsigned*)&x[(size_t)s * NH + lane * 2];
        a0 += b2f((unsigned short)(u & 0xffff));
        a1 += b2f((unsigned short)(u >> 16));
    }
    const int d = end - beg;
    const float inv = 1.f / (float)(d > 0 ? d : 1);
    const unsigned o = (unsigned)(unsigned short)f2b(a0 * inv) | ((unsigned)(unsigned short)f2b(a1 * inv) << 16);
    *(unsigned*)&mean[(size_t)n * NH + lane * 2] = o;
}

// ============ GCN layer: out = relu(x*Ws + mean*Wm + b), bf16 MFMA, K=256 ============
__global__ __launch_bounds__(256) void k_gcn(const short* __restrict__ x, const short* __restrict__ mean,
                                             const short* __restrict__ Wt, const float* __restrict__ b,
                                             short* __restrict__ out) {
    __shared__ short At[128 * 40];
    __shared__ short Bt[128 * 40];
    __shared__ float bs[128];
    const int n0 = blockIdx.x * 128;
    const int tid = threadIdx.x;
    const int lane = tid & 63, wid = tid >> 6;
    const int wr = wid >> 1, wc = wid & 1;
    if (tid < 128) bs[tid] = b[tid];

    f32x4 acc[4][4] = {};

    for (int kc = 0; kc < 8; ++kc) {
        const short* Asrc = (kc < 4) ? x : mean;
        const int ko = (kc & 3) * 32;
        __syncthreads();
        {
            const int nl = tid >> 1, seg = tid & 1;
            const int gn = n0 + nl;
            short8 v0 = {0,0,0,0,0,0,0,0}, v1 = {0,0,0,0,0,0,0,0};
            if (gn < NSRC) {
                v0 = *(const short8*)&Asrc[(size_t)gn * NH + ko + seg * 16];
                v1 = *(const short8*)&Asrc[(size_t)gn * NH + ko + seg * 16 + 8];
            }
            *(short8*)&At[nl * 40 + seg * 16] = v0;
            *(short8*)&At[nl * 40 + seg * 16 + 8] = v1;
        }
        {
            const int h = tid >> 1, seg = tid & 1;
            const short8 w0 = *(const short8*)&Wt[h * 256 + kc * 32 + seg * 16];
            const short8 w1 = *(const short8*)&Wt[h * 256 + kc * 32 + seg * 16 + 8];
            *(short8*)&Bt[h * 40 + seg * 16] = w0;
            *(short8*)&Bt[h * 40 + seg * 16 + 8] = w1;
        }
        __syncthreads();
        const int kb = (lane >> 4) * 8;
        short8 a[4], bb[4];
        #pragma unroll
        for (int i = 0; i < 4; ++i) a[i] = *(const short8*)&At[(wr * 64 + i * 16 + (lane & 15)) * 40 + kb];
        #pragma unroll
        for (int j = 0; j < 4; ++j) bb[j] = *(const short8*)&Bt[(wc * 64 + j * 16 + (lane & 15)) * 40 + kb];
        #pragma unroll
        for (int i = 0; i < 4; ++i)
            #pragma unroll
            for (int j = 0; j < 4; ++j)
                acc[i][j] = __builtin_amdgcn_mfma_f32_16x16x32_bf16(a[i], bb[j], acc[i][j], 0, 0, 0);
    }
    #pragma unroll
    for (int i = 0; i < 4; ++i)
        #pragma unroll
        for (int j = 0; j < 4; ++j) {
            const int h = wc * 64 + j * 16 + (lane & 15);
            #pragma unroll
            for (int rr = 0; rr < 4; ++rr) {
                const int n = n0 + wr * 64 + i * 16 + (lane >> 4) * 4 + rr;
                if (n < NSRC) out[(size_t)n * NH + h] = f2b(fmaxf(acc[i][j][rr] + bs[h], 0.f));
            }
        }
}

// ============ J = x * W_out^T + b_out (bf16 MFMA, fp32 out) ============
__global__ __launch_bounds__(256) void k_out(const short* __restrict__ x, const short* __restrict__ Wob,
                                             const float* __restrict__ bout, float* __restrict__ J) {
    __shared__ short At[128 * 40];
    __shared__ short Bt[128 * 40];
    __shared__ float bs[128];
    const int n0 = blockIdx.x * 128;
    const int t0 = blockIdx.y * 128;
    const int tid = threadIdx.x;
    const int lane = tid & 63, wid = tid >> 6;
    const int wr = wid >> 1, wc = wid & 1;
    if (tid < 128) bs[tid] = bout[t0 + tid];

    f32x4 acc[4][4] = {};

    for (int kc = 0; kc < 4; ++kc) {
        __syncthreads();
        {
            const int nl = tid >> 1, seg = tid & 1;
            const int gn = n0 + nl;
            short8 v0 = {0,0,0,0,0,0,0,0}, v1 = {0,0,0,0,0,0,0,0};
            if (gn < NSRC) {
                v0 = *(const short8*)&x[(size_t)gn * NH + kc * 32 + seg * 16];
                v1 = *(const short8*)&x[(size_t)gn * NH + kc * 32 + seg * 16 + 8];
            }
            *(short8*)&At[nl * 40 + seg * 16] = v0;
            *(short8*)&At[nl * 40 + seg * 16 + 8] = v1;
        }
        {
            const int tl = tid >> 1, seg = tid & 1;
            const short8 w0 = *(const short8*)&Wob[(t0 + tl) * NH + kc * 32 + seg * 16];
            const short8 w1 = *(const short8*)&Wob[(t0 + tl) * NH + kc * 32 + seg * 16 + 8];
            *(short8*)&Bt[tl * 40 + seg * 16] = w0;
            *(short8*)&Bt[tl * 40 + seg * 16 + 8] = w1;
        }
        __syncthreads();
        const int kb = (lane >> 4) * 8;
        short8 a[4], bb[4];
        #pragma unroll
        for (int i = 0; i < 4; ++i) a[i] = *(const short8*)&At[(wr * 64 + i * 16 + (lane & 15)) * 40 + kb];
        #pragma unroll
        for (int j = 0; j < 4; ++j) bb[j] = *(const short8*)&Bt[(wc * 64 + j * 16 + (lane & 15)) * 40 + kb];
        #pragma unroll
        for (int i = 0; i < 4; ++i)
            #pragma unroll
            for (int j = 0; j < 4; ++j)
                acc[i][j] = __builtin_amdgcn_mfma_f32_16x16x32_bf16(a[i], bb[j], acc[i][j], 0, 0, 0);
    }
    #pragma unroll
    for (int i = 0; i < 4; ++i)
        #pragma unroll
        for (int j = 0; j < 4; ++j) {
            const int tl = wc * 64 + j * 16 + (lane & 15);   // block-local time index
            const int t = t0 + tl;
            #pragma unroll
            for (int rr = 0; rr < 4; ++rr) {
                const int n = n0 + wr * 64 + i * 16 + (lane >> 4) * 4 + rr;
                if (n < NSRC) J[(size_t)n * NT + t] = acc[i][j][rr] + bs[tl];
            }
        }
}

extern "C" void kernel_launch(void* const* d_in, const int* in_sizes, int n_in,
                              void* d_out, int out_size, void* d_ws, size_t ws_size,
                              hipStream_t stream) {
    const float* Y      = (const float*)d_in[0];
    const float* L      = (const float*)d_in[1];
    const float* vf     = (const float*)d_in[2];
    const int*   send   = (const int*)d_in[3];
    const int*   recv   = (const int*)d_in[4];
    const float* W_in   = (const float*)d_in[5];
    const float* b_in   = (const float*)d_in[6];
    const float* W_self = (const float*)d_in[7];
    const float* W_msg  = (const float*)d_in[8];
    const float* b_lay  = (const float*)d_in[9];
    const float* W_out  = (const float*)d_in[10];
    const float* b_out  = (const float*)d_in[11];
    float* out = (float*)d_out;

    char* ws = (char*)d_ws;
    size_t off = 0;
    auto alloc = [&](size_t bytes) -> void* {
        void* p = ws + off;
        off += (bytes + 255) & ~(size_t)255;
        return p;
    };
    // big region: Gp (125*320*320*4 = 51.2MB) reused later as xA+xB (2*100000*128*2 = 51.2MB)
    char* big    = (char*)alloc((size_t)GP_SPLIT * 320 * 320 * 4);
    float* Gp    = (float*)big;
    short* xA    = (short*)big;
    short* xB    = (short*)(big + (size_t)NSRC * NH * 2);
    float* G     = (float*)alloc((size_t)320 * 320 * 4);
    float* Yw    = (float*)alloc((size_t)NSEN * 128 * 4);
    short* Zt    = (short*)alloc((size_t)NH * 352 * 2);
    short* WtL   = (short*)alloc((size_t)NL * NH * 256 * 2);
    short* Wob   = (short*)alloc((size_t)NT * NH * 2);
    int* rowptr  = (int*)alloc((size_t)(NSRC + 1) * 4);
    int* cursor  = (int*)alloc((size_t)NSRC * 4);
    int* cnt     = (int*)alloc((size_t)NSRC * 4);
    int* csr     = (int*)alloc((size_t)NE * 4);

    hipMemsetAsync(cnt, 0, (size_t)NSRC * 4, stream);
    hipMemsetAsync(Zt, 0, (size_t)NH * 352 * 2, stream);

    k_prep<<<(3 * 128 * 256 + 256 * 128 + 128 * 8 + 255) / 256, 256, 0, stream>>>(
        W_self, W_msg, W_out, W_in, WtL, Wob, Zt);
    k_Yw<<<NSEN, 128, 0, stream>>>(Y, W_in, Yw);

    k_hist<<<(NE + 255) / 256, 256, 0, stream>>>(recv, cnt);
    k_scan<<<1, 1024, 0, stream>>>(cnt, rowptr);
    hipMemcpyAsync(cursor, rowptr, (size_t)NSRC * 4, hipMemcpyDeviceToDevice, stream);
    k_fill<<<(NE + 255) / 256, 256, 0, stream>>>(send, recv, cursor, csr);

    k_gram_p1<<<256, 512, 0, stream>>>(L, Gp);
    k_gram_p2<<<(320 * 320 + 255) / 256, 256, 0, stream>>>(Gp, G);
    k_solve<<<64, 256, 0, stream>>>(G, Yw, Zt);
    k_x0<<<(NSRC + 127) / 128, 256, 0, stream>>>(L, Zt, vf, b_in, xA);   // overwrites Gp (dead)

    short* x = xA;
    short* m = xB;
    for (int l = 0; l < NL; ++l) {
        k_agg<<<(NSRC + 3) / 4, 256, 0, stream>>>(x, rowptr, csr, m);
        k_gcn<<<(NSRC + 127) / 128, 256, 0, stream>>>(
            x, m, WtL + (size_t)l * NH * 256, b_lay + (size_t)l * NH, m);
        short* t = x; x = m; m = t;
    }
    k_out<<<dim3((NSRC + 127) / 128, 2), 256, 0, stream>>>(x, Wob, b_out, out);
}

// Round 9
// 775.277 us; speedup vs baseline: 2.7018x; 1.1196x over previous
//
#include <hip/hip_runtime.h>

#define NSRC 100000
#define NSEN 306
#define NT 256
#define NF 8
#define NH 128
#define NL 3
#define NE 600000
#define JITERS 6

#define GP_SPLIT 125
#define GP_CHUNK 800   // 125*800 = 100000 exactly

#define SCAN_BLOCKS 49  // ceil(100000 / 2048)

typedef short short8 __attribute__((ext_vector_type(8)));
typedef float f32x4 __attribute__((ext_vector_type(4)));

__device__ __forceinline__ short f2b(float f) {
    union { float f; unsigned u; } v; v.f = f;
    unsigned r = v.u + 0x7fffu + ((v.u >> 16) & 1u);
    return (short)(r >> 16);
}
__device__ __forceinline__ float b2f(unsigned short s) {
    union { unsigned u; float f; } v; v.u = ((unsigned)s) << 16;
    return v.f;
}

// ============ gram phase 1: Gp[p] = L[:,chunk_p] * L[:,chunk_p]^T (bf16 MFMA) ============
__global__ __launch_bounds__(512) void k_gram_p1(const float* __restrict__ L, float* __restrict__ Gp) {
    __shared__ short T[320 * 72];  // rows 0..319 of L (bf16), 64 k-cols, pad stride 72
    const int bid = blockIdx.x;
    const int g = bid >> 4, r = bid & 15;
    const int p = g * 8 + (r & 7);          // k-chunk index
    if (p >= GP_SPLIT) return;
    const int bi = r >> 3;                  // row half: 0 or 1
    const int c0 = p * GP_CHUNK;
    const int cend = c0 + GP_CHUNK;
    const int tid = threadIdx.x;
    const int lane = tid & 63, wid = tid >> 6;
    const int wr = wid >> 2, wc = wid & 3;  // 2x4 waves, each 80x80

    f32x4 acc[5][5] = {};

    for (int s0 = c0; s0 < cend; s0 += 64) {
        __syncthreads();
        for (int task = tid; task < 640; task += 512) {
            const int row = task >> 1, half = task & 1;
            const int col = s0 + half * 32;
            const bool ok = (row < NSEN) && (col + 31 < cend);
            const float* src = L + (size_t)row * NSRC + col;
            #pragma unroll
            for (int q = 0; q < 4; ++q) {
                float4 f0 = make_float4(0.f, 0.f, 0.f, 0.f);
                float4 f1 = make_float4(0.f, 0.f, 0.f, 0.f);
                if (ok) { f0 = *(const float4*)(src + q * 8); f1 = *(const float4*)(src + q * 8 + 4); }
                short8 t;
                t[0] = f2b(f0.x); t[1] = f2b(f0.y); t[2] = f2b(f0.z); t[3] = f2b(f0.w);
                t[4] = f2b(f1.x); t[5] = f2b(f1.y); t[6] = f2b(f1.z); t[7] = f2b(f1.w);
                *(short8*)&T[row * 72 + half * 32 + q * 8] = t;
            }
        }
        __syncthreads();
        #pragma unroll
        for (int ks = 0; ks < 2; ++ks) {
            const int kb = ks * 32 + (lane >> 4) * 8;
            short8 a[5], b[5];
            #pragma unroll
            for (int i = 0; i < 5; ++i) {
                a[i] = *(const short8*)&T[(bi * 160 + wr * 80 + i * 16 + (lane & 15)) * 72 + kb];
                b[i] = *(const short8*)&T[(wc * 80 + i * 16 + (lane & 15)) * 72 + kb];
            }
            #pragma unroll
            for (int i = 0; i < 5; ++i)
                #pragma unroll
                for (int j = 0; j < 5; ++j)
                    acc[i][j] = __builtin_amdgcn_mfma_f32_16x16x32_bf16(a[i], b[j], acc[i][j], 0, 0, 0);
        }
    }
    float* dst = Gp + (size_t)p * 320 * 320;
    #pragma unroll
    for (int i = 0; i < 5; ++i)
        #pragma unroll
        for (int j = 0; j < 5; ++j) {
            const int gj = wc * 80 + j * 16 + (lane & 15);
            #pragma unroll
            for (int rr = 0; rr < 4; ++rr) {
                const int gi = bi * 160 + wr * 80 + i * 16 + (lane >> 4) * 4 + rr;
                dst[gi * 320 + gj] = acc[i][j][rr];
            }
        }
}

// ============ gram phase 2: G = sum_p Gp[p], + reg^2 on diag ============
__global__ void k_gram_p2(const float* __restrict__ Gp, float* __restrict__ G) {
    const int idx = blockIdx.x * 256 + threadIdx.x;
    if (idx >= 320 * 320) return;
    float s = 0.f;
    for (int p = 0; p < GP_SPLIT; ++p) s += Gp[(size_t)p * 102400 + idx];
    if ((idx / 320) == (idx % 320)) s += 1e-6f;
    G[idx] = s;
}

// ============ Yw = Y * W_in[:, :256]^T  (306 x 128, fp32) ============
__global__ __launch_bounds__(128) void k_Yw(const float* __restrict__ Y, const float* __restrict__ W_in,
                                            float* __restrict__ Yw) {
    __shared__ float ys[NT];
    const int i = blockIdx.x, h = threadIdx.x;
    ys[h] = Y[i * NT + h];
    ys[h + 128] = Y[i * NT + h + 128];
    __syncthreads();
    const float* w = W_in + (size_t)h * (NT + NF);
    float acc = 0.f;
    #pragma unroll 4
    for (int t = 0; t < NT; ++t) acc = fmaf(ys[t], w[t], acc);
    Yw[i * 128 + h] = acc;
}

// ===== fused Jacobi solve in Z-space: G Z = Yw (306x128), 6 iters, writes Zt bf16 =====
__global__ __launch_bounds__(256) void k_solve(const float* __restrict__ G, const float* __restrict__ Yw,
                                               short* __restrict__ Zt) {
    __shared__ float Xl[320 * 2];
    const int c0 = blockIdx.x * 2;
    const int tid = threadIdx.x;
    const int i1 = tid;
    const int i2 = 256 + tid;
    const bool has2 = i2 < NSEN;
    const int i2c = has2 ? i2 : 0;

    const float d1i = 1.f / G[i1 * 320 + i1];
    const float d2i = has2 ? (1.f / G[i2c * 320 + i2c]) : 0.f;
    float y1[2], y2[2], x1[2], x2[2];
    y1[0] = Yw[i1 * 128 + c0]; y1[1] = Yw[i1 * 128 + c0 + 1];
    y2[0] = has2 ? Yw[i2 * 128 + c0] : 0.f;
    y2[1] = has2 ? Yw[i2 * 128 + c0 + 1] : 0.f;
    x1[0] = y1[0] * d1i; x1[1] = y1[1] * d1i;
    x2[0] = y2[0] * d2i; x2[1] = y2[1] * d2i;
    Xl[i1 * 2] = x1[0]; Xl[i1 * 2 + 1] = x1[1];
    if (has2)      { Xl[i2 * 2] = x2[0]; Xl[i2 * 2 + 1] = x2[1]; }
    else if (tid < 64) { Xl[i2 * 2] = 0.f; Xl[i2 * 2 + 1] = 0.f; }  // zero rows 306..319
    __syncthreads();

    for (int it = 0; it < JITERS; ++it) {
        float r1[2] = {y1[0], y1[1]};
        float r2[2] = {y2[0], y2[1]};
        for (int k0 = 0; k0 < 320; k0 += 8) {
            float g1[8], g2[8];
            float2 xx[8];
            #pragma unroll
            for (int u = 0; u < 8; ++u) {
                g1[u] = G[(k0 + u) * 320 + i1];
                g2[u] = G[(k0 + u) * 320 + i2c];
                xx[u] = *(const float2*)&Xl[(k0 + u) * 2];
            }
            #pragma unroll
            for (int u = 0; u < 8; ++u) {
                r1[0] = fmaf(-g1[u], xx[u].x, r1[0]);
                r1[1] = fmaf(-g1[u], xx[u].y, r1[1]);
                r2[0] = fmaf(-g2[u], xx[u].x, r2[0]);
                r2[1] = fmaf(-g2[u], xx[u].y, r2[1]);
            }
        }
        __syncthreads();
        x1[0] += r1[0] * d1i; x1[1] += r1[1] * d1i;
        x2[0] += r2[0] * d2i; x2[1] += r2[1] * d2i;
        Xl[i1 * 2] = x1[0]; Xl[i1 * 2 + 1] = x1[1];
        if (has2) { Xl[i2 * 2] = x2[0]; Xl[i2 * 2 + 1] = x2[1]; }
        __syncthreads();
    }
    Zt[(c0) * 352 + i1]     = f2b(x1[0]);
    Zt[(c0 + 1) * 352 + i1] = f2b(x1[1]);
    if (has2) {
        Zt[(c0) * 352 + i2]     = f2b(x2[0]);
        Zt[(c0 + 1) * 352 + i2] = f2b(x2[1]);
    }
}

// ============ prep: WtL (3x[h][256] = [Ws^T|Wm^T]), Wob, Zt wf columns ============
__global__ void k_prep(const float* __restrict__ W_self, const float* __restrict__ W_msg,
                       const float* __restrict__ W_out, const float* __restrict__ W_in,
                       short* __restrict__ WtL, short* __restrict__ Wob, short* __restrict__ Zt) {
    const int idx = blockIdx.x * 256 + threadIdx.x;
    if (idx < 3 * 128 * 256) {
        const int l = idx >> 15, rem = idx & 32767;
        const int h = rem >> 8, k = rem & 255;
        float v = (k < 128) ? W_self[l * 16384 + k * 128 + h] : W_msg[l * 16384 + (k - 128) * 128 + h];
        WtL[idx] = f2b(v);
    } else if (idx < 3 * 128 * 256 + 256 * 128) {
        const int j = idx - 3 * 128 * 256;
        Wob[j] = f2b(W_out[j]);
    } else if (idx < 3 * 128 * 256 + 256 * 128 + 128 * 8) {
        const int j = idx - (3 * 128 * 256 + 256 * 128);
        const int h = j >> 3, f = j & 7;
        Zt[h * 352 + 320 + f] = f2b(W_in[(size_t)h * (NT + NF) + NT + f]);
    }
}

// ============ x0 = L^T Z + vf*wf^T + b_in (MFMA; vf folded in as K=320..327) ============
__global__ __launch_bounds__(256) void k_x0(const float* __restrict__ L, const short* __restrict__ Zt,
                                            const float* __restrict__ vf, const float* __restrict__ b_in,
                                            short* __restrict__ xout) {
    __shared__ short At[128 * 40];
    __shared__ short Bt[128 * 40];
    __shared__ float bs[128];
    const int n0 = blockIdx.x * 128;
    const int tid = threadIdx.x;
    const int lane = tid & 63, wid = tid >> 6;
    const int wr = wid >> 1, wc = wid & 1;
    if (tid < 128) bs[tid] = b_in[tid];

    f32x4 acc[4][4] = {};

    for (int s0 = 0; s0 <= 320; s0 += 32) {
        __syncthreads();
        {   // A stage: At[n][s] = L[s][n] (transposed) or vf fold (s0==320)
            const int s_loc = tid >> 3, nseg = (tid & 7) * 16;
            float v[16];
            if (s0 < 320) {
                const int srow = s0 + s_loc;
                const bool okrow = srow < NSEN;
                const float* src = L + (size_t)srow * NSRC + n0 + nseg;
                #pragma unroll
                for (int i = 0; i < 16; i += 4) {
                    float4 f = make_float4(0.f, 0.f, 0.f, 0.f);
                    const int gn = n0 + nseg + i;
                    if (okrow) {
                        if (gn + 3 < NSRC) f = *(const float4*)(src + i);
                        else {
                            if (gn < NSRC) f.x = src[i];
                            if (gn + 1 < NSRC) f.y = src[i + 1];
                            if (gn + 2 < NSRC) f.z = src[i + 2];
                        }
                    }
                    v[i] = f.x; v[i + 1] = f.y; v[i + 2] = f.z; v[i + 3] = f.w;
                }
            } else {
                #pragma unroll
                for (int i = 0; i < 16; ++i) {
                    const int gn = n0 + nseg + i;
                    v[i] = (s_loc < NF && gn < NSRC) ? vf[(size_t)gn * NF + s_loc] : 0.f;
                }
            }
            #pragma unroll
            for (int i = 0; i < 16; ++i) At[(nseg + i) * 40 + s_loc] = f2b(v[i]);
        }
        {   // B stage: Bt[h][0..31] = Zt[h][s0..s0+31]
            const int h = tid >> 1, seg = tid & 1;
            const short8 z0 = *(const short8*)&Zt[h * 352 + s0 + seg * 16];
            const short8 z1 = *(const short8*)&Zt[h * 352 + s0 + seg * 16 + 8];
            *(short8*)&Bt[h * 40 + seg * 16] = z0;
            *(short8*)&Bt[h * 40 + seg * 16 + 8] = z1;
        }
        __syncthreads();
        const int kb = (lane >> 4) * 8;
        short8 a[4], b[4];
        #pragma unroll
        for (int i = 0; i < 4; ++i) a[i] = *(const short8*)&At[(wr * 64 + i * 16 + (lane & 15)) * 40 + kb];
        #pragma unroll
        for (int j = 0; j < 4; ++j) b[j] = *(const short8*)&Bt[(wc * 64 + j * 16 + (lane & 15)) * 40 + kb];
        #pragma unroll
        for (int i = 0; i < 4; ++i)
            #pragma unroll
            for (int j = 0; j < 4; ++j)
                acc[i][j] = __builtin_amdgcn_mfma_f32_16x16x32_bf16(a[i], b[j], acc[i][j], 0, 0, 0);
    }
    #pragma unroll
    for (int i = 0; i < 4; ++i)
        #pragma unroll
        for (int j = 0; j < 4; ++j) {
            const int h = wc * 64 + j * 16 + (lane & 15);
            #pragma unroll
            for (int rr = 0; rr < 4; ++rr) {
                const int n = n0 + wr * 64 + i * 16 + (lane >> 4) * 4 + rr;
                if (n < NSRC) xout[(size_t)n * NH + h] = f2b(acc[i][j][rr] + bs[h]);
            }
        }
}

// ============ CSR build ============
__global__ void k_hist(const int* __restrict__ recv, int* __restrict__ cnt) {
    int e = blockIdx.x * 256 + threadIdx.x;
    if (e < NE) atomicAdd(&cnt[recv[e]], 1);
}

// --- 3-phase multi-block exclusive scan of cnt[NSRC] -> rowptr ---
__global__ __launch_bounds__(256) void k_scan1(const int* __restrict__ cnt, int* __restrict__ bsum) {
    __shared__ int sd[256];
    const int tid = threadIdx.x;
    const int base = blockIdx.x * 2048 + tid * 8;
    int s = 0;
    if (base + 8 <= NSRC) {
        int4 a = *(const int4*)(cnt + base);
        int4 b = *(const int4*)(cnt + base + 4);
        s = a.x + a.y + a.z + a.w + b.x + b.y + b.z + b.w;
    } else {
        for (int j = 0; j < 8; ++j) if (base + j < NSRC) s += cnt[base + j];
    }
    sd[tid] = s;
    __syncthreads();
    for (int d = 128; d > 0; d >>= 1) {
        if (tid < d) sd[tid] += sd[tid + d];
        __syncthreads();
    }
    if (tid == 0) bsum[blockIdx.x] = sd[0];
}

__global__ void k_scan2(int* __restrict__ bsum, int* __restrict__ rowptr) {
    const int tid = threadIdx.x;  // 64 threads, one wave
    const int v0 = (tid < SCAN_BLOCKS) ? bsum[tid] : 0;
    int v = v0;
    #pragma unroll
    for (int d = 1; d < 64; d <<= 1) {
        int n = __shfl_up(v, d);
        if (tid >= d) v += n;
    }
    if (tid < SCAN_BLOCKS) bsum[tid] = v - v0;          // exclusive block offset
    if (tid == SCAN_BLOCKS - 1) rowptr[NSRC] = v;       // total
}

__global__ __launch_bounds__(256) void k_scan3(const int* __restrict__ cnt, const int* __restrict__ bsum,
                                               int* __restrict__ rowptr) {
    __shared__ int sd[256];
    const int tid = threadIdx.x;
    const int base = blockIdx.x * 2048 + tid * 8;
    int v[8];
    int s = 0;
    #pragma unroll
    for (int j = 0; j < 8; ++j) { v[j] = (base + j < NSRC) ? cnt[base + j] : 0; s += v[j]; }
    sd[tid] = s;
    __syncthreads();
    for (int d = 1; d < 256; d <<= 1) {
        int add = (tid >= d) ? sd[tid - d] : 0;
        __syncthreads();
        sd[tid] += add;
        __syncthreads();
    }
    int run = sd[tid] - s + bsum[blockIdx.x];   // exclusive prefix for this thread's 8
    #pragma unroll
    for (int j = 0; j < 8; ++j) { if (base + j < NSRC) rowptr[base + j] = run; run += v[j]; }
}

__global__ void k_fill(const int* __restrict__ send, const int* __restrict__ recv,
                       int* __restrict__ cursor, int* __restrict__ csr) {
    int e = blockIdx.x * 256 + threadIdx.x;
    if (e < NE) {
        int pos = atomicAdd(&cursor[recv[e]], 1);
        csr[pos] = send[e];
    }
}

// ============ mean aggregation over bf16 activations (pull, 1 wave / node) ============
__global__ __launch_bounds__(256) void k_agg(const short* __restrict__ x, const int* __restrict__ rowptr,
                                             const int* __restrict__ csr, short* __restrict__ mean) {
    const int lane = threadIdx.x & 63;
    const int n = blockIdx.x * 4 + (threadIdx.x >> 6);
    if (n >= NSRC) return;
    const int beg = rowptr[n], end = rowptr[n + 1];
    float a0 = 0.f, a1 = 0.f;
    for (int e = beg; e < end; ++e) {
        const int s = csr[e];
        const unsigned u = *(const unsigned*)&x[(size_t)s * NH + lane * 2];
        a0 += b2f((unsigned short)(u & 0xffff));
        a1 += b2f((unsigned short)(u >> 16));
    }
    const int d = end - beg;
    const float inv = 1.f / (float)(d > 0 ? d : 1);
    const unsigned o = (unsigned)(unsigned short)f2b(a0 * inv) | ((unsigned)(unsigned short)f2b(a1 * inv) << 16);
    *(unsigned*)&mean[(size_t)n * NH + lane * 2] = o;
}

// ============ GCN layer: out = relu(x*Ws + mean*Wm + b), bf16 MFMA, K=256 ============
__global__ __launch_bounds__(256) void k_gcn(const short* __restrict__ x, const short* __restrict__ mean,
                                             const short* __restrict__ Wt, const float* __restrict__ b,
                                             short* __restrict__ out) {
    __shared__ short At[128 * 40];
    __shared__ short Bt[128 * 40];
    __shared__ float bs[128];
    const int n0 = blockIdx.x * 128;
    const int tid = threadIdx.x;
    const int lane = tid & 63, wid = tid >> 6;
    const int wr = wid >> 1, wc = wid & 1;
    if (tid < 128) bs[tid] = b[tid];

    f32x4 acc[4][4] = {};

    for (int kc = 0; kc < 8; ++kc) {
        const short* Asrc = (kc < 4) ? x : mean;
        const int ko = (kc & 3) * 32;
        __syncthreads();
        {
            const int nl = tid >> 1, seg = tid & 1;
            const int gn = n0 + nl;
            short8 v0 = {0,0,0,0,0,0,0,0}, v1 = {0,0,0,0,0,0,0,0};
            if (gn < NSRC) {
                v0 = *(const short8*)&Asrc[(size_t)gn * NH + ko + seg * 16];
                v1 = *(const short8*)&Asrc[(size_t)gn * NH + ko + seg * 16 + 8];
            }
            *(short8*)&At[nl * 40 + seg * 16] = v0;
            *(short8*)&At[nl * 40 + seg * 16 + 8] = v1;
        }
        {
            const int h = tid >> 1, seg = tid & 1;
            const short8 w0 = *(const short8*)&Wt[h * 256 + kc * 32 + seg * 16];
            const short8 w1 = *(const short8*)&Wt[h * 256 + kc * 32 + seg * 16 + 8];
            *(short8*)&Bt[h * 40 + seg * 16] = w0;
            *(short8*)&Bt[h * 40 + seg * 16 + 8] = w1;
        }
        __syncthreads();
        const int kb = (lane >> 4) * 8;
        short8 a[4], bb[4];
        #pragma unroll
        for (int i = 0; i < 4; ++i) a[i] = *(const short8*)&At[(wr * 64 + i * 16 + (lane & 15)) * 40 + kb];
        #pragma unroll
        for (int j = 0; j < 4; ++j) bb[j] = *(const short8*)&Bt[(wc * 64 + j * 16 + (lane & 15)) * 40 + kb];
        #pragma unroll
        for (int i = 0; i < 4; ++i)
            #pragma unroll
            for (int j = 0; j < 4; ++j)
                acc[i][j] = __builtin_amdgcn_mfma_f32_16x16x32_bf16(a[i], bb[j], acc[i][j], 0, 0, 0);
    }
    #pragma unroll
    for (int i = 0; i < 4; ++i)
        #pragma unroll
        for (int j = 0; j < 4; ++j) {
            const int h = wc * 64 + j * 16 + (lane & 15);
            #pragma unroll
            for (int rr = 0; rr < 4; ++rr) {
                const int n = n0 + wr * 64 + i * 16 + (lane >> 4) * 4 + rr;
                if (n < NSRC) out[(size_t)n * NH + h] = f2b(fmaxf(acc[i][j][rr] + bs[h], 0.f));
            }
        }
}

// ============ J = x * W_out^T + b_out (bf16 MFMA, fp32 out) ============
__global__ __launch_bounds__(256) void k_out(const short* __restrict__ x, const short* __restrict__ Wob,
                                             const float* __restrict__ bout, float* __restrict__ J) {
    __shared__ short At[128 * 40];
    __shared__ short Bt[128 * 40];
    __shared__ float bs[128];
    const int n0 = blockIdx.x * 128;
    const int t0 = blockIdx.y * 128;
    const int tid = threadIdx.x;
    const int lane = tid & 63, wid = tid >> 6;
    const int wr = wid >> 1, wc = wid & 1;
    if (tid < 128) bs[tid] = bout[t0 + tid];

    f32x4 acc[4][4] = {};

    for (int kc = 0; kc < 4; ++kc) {
        __syncthreads();
        {
            const int nl = tid >> 1, seg = tid & 1;
            const int gn = n0 + nl;
            short8 v0 = {0,0,0,0,0,0,0,0}, v1 = {0,0,0,0,0,0,0,0};
            if (gn < NSRC) {
                v0 = *(const short8*)&x[(size_t)gn * NH + kc * 32 + seg * 16];
                v1 = *(const short8*)&x[(size_t)gn * NH + kc * 32 + seg * 16 + 8];
            }
            *(short8*)&At[nl * 40 + seg * 16] = v0;
            *(short8*)&At[nl * 40 + seg * 16 + 8] = v1;
        }
        {
            const int tl = tid >> 1, seg = tid & 1;
            const short8 w0 = *(const short8*)&Wob[(t0 + tl) * NH + kc * 32 + seg * 16];
            const short8 w1 = *(const short8*)&Wob[(t0 + tl) * NH + kc * 32 + seg * 16 + 8];
            *(short8*)&Bt[tl * 40 + seg * 16] = w0;
            *(short8*)&Bt[tl * 40 + seg * 16 + 8] = w1;
        }
        __syncthreads();
        const int kb = (lane >> 4) * 8;
        short8 a[4], bb[4];
        #pragma unroll
        for (int i = 0; i < 4; ++i) a[i] = *(const short8*)&At[(wr * 64 + i * 16 + (lane & 15)) * 40 + kb];
        #pragma unroll
        for (int j = 0; j < 4; ++j) bb[j] = *(const short8*)&Bt[(wc * 64 + j * 16 + (lane & 15)) * 40 + kb];
        #pragma unroll
        for (int i = 0; i < 4; ++i)
            #pragma unroll
            for (int j = 0; j < 4; ++j)
                acc[i][j] = __builtin_amdgcn_mfma_f32_16x16x32_bf16(a[i], bb[j], acc[i][j], 0, 0, 0);
    }
    #pragma unroll
    for (int i = 0; i < 4; ++i)
        #pragma unroll
        for (int j = 0; j < 4; ++j) {
            const int tl = wc * 64 + j * 16 + (lane & 15);   // block-local time index
            const int t = t0 + tl;
            #pragma unroll
            for (int rr = 0; rr < 4; ++rr) {
                const int n = n0 + wr * 64 + i * 16 + (lane >> 4) * 4 + rr;
                if (n < NSRC) J[(size_t)n * NT + t] = acc[i][j][rr] + bs[tl];
            }
        }
}

extern "C" void kernel_launch(void* const* d_in, const int* in_sizes, int n_in,
                              void* d_out, int out_size, void* d_ws, size_t ws_size,
                              hipStream_t stream) {
    const float* Y      = (const float*)d_in[0];
    const float* L      = (const float*)d_in[1];
    const float* vf     = (const float*)d_in[2];
    const int*   send   = (const int*)d_in[3];
    const int*   recv   = (const int*)d_in[4];
    const float* W_in   = (const float*)d_in[5];
    const float* b_in   = (const float*)d_in[6];
    const float* W_self = (const float*)d_in[7];
    const float* W_msg  = (const float*)d_in[8];
    const float* b_lay  = (const float*)d_in[9];
    const float* W_out  = (const float*)d_in[10];
    const float* b_out  = (const float*)d_in[11];
    float* out = (float*)d_out;

    char* ws = (char*)d_ws;
    size_t off = 0;
    auto alloc = [&](size_t bytes) -> void* {
        void* p = ws + off;
        off += (bytes + 255) & ~(size_t)255;
        return p;
    };
    // big region: Gp (125*320*320*4 = 51.2MB) reused later as xA+xB (2*100000*128*2 = 51.2MB)
    char* big    = (char*)alloc((size_t)GP_SPLIT * 320 * 320 * 4);
    float* Gp    = (float*)big;
    short* xA    = (short*)big;
    short* xB    = (short*)(big + (size_t)NSRC * NH * 2);
    float* G     = (float*)alloc((size_t)320 * 320 * 4);
    float* Yw    = (float*)alloc((size_t)NSEN * 128 * 4);
    short* Zt    = (short*)alloc((size_t)NH * 352 * 2);
    short* WtL   = (short*)alloc((size_t)NL * NH * 256 * 2);
    short* Wob   = (short*)alloc((size_t)NT * NH * 2);
    int* rowptr  = (int*)alloc((size_t)(NSRC + 1) * 4);
    int* cursor  = (int*)alloc((size_t)NSRC * 4);
    int* cnt     = (int*)alloc((size_t)NSRC * 4);
    int* bsum    = (int*)alloc((size_t)64 * 4);
    int* csr     = (int*)alloc((size_t)NE * 4);

    hipMemsetAsync(cnt, 0, (size_t)NSRC * 4, stream);
    hipMemsetAsync(Zt, 0, (size_t)NH * 352 * 2, stream);

    k_prep<<<(3 * 128 * 256 + 256 * 128 + 128 * 8 + 255) / 256, 256, 0, stream>>>(
        W_self, W_msg, W_out, W_in, WtL, Wob, Zt);
    k_Yw<<<NSEN, 128, 0, stream>>>(Y, W_in, Yw);

    k_hist<<<(NE + 255) / 256, 256, 0, stream>>>(recv, cnt);
    k_scan1<<<SCAN_BLOCKS, 256, 0, stream>>>(cnt, bsum);
    k_scan2<<<1, 64, 0, stream>>>(bsum, rowptr);
    k_scan3<<<SCAN_BLOCKS, 256, 0, stream>>>(cnt, bsum, rowptr);
    hipMemcpyAsync(cursor, rowptr, (size_t)NSRC * 4, hipMemcpyDeviceToDevice, stream);
    k_fill<<<(NE + 255) / 256, 256, 0, stream>>>(send, recv, cursor, csr);

    k_gram_p1<<<256, 512, 0, stream>>>(L, Gp);
    k_gram_p2<<<(320 * 320 + 255) / 256, 256, 0, stream>>>(Gp, G);
    k_solve<<<64, 256, 0, stream>>>(G, Yw, Zt);
    k_x0<<<(NSRC + 127) / 128, 256, 0, stream>>>(L, Zt, vf, b_in, xA);   // overwrites Gp (dead)

    short* x = xA;
    short* m = xB;
    for (int l = 0; l < NL; ++l) {
        k_agg<<<(NSRC + 3) / 4, 256, 0, stream>>>(x, rowptr, csr, m);
        k_gcn<<<(NSRC + 127) / 128, 256, 0, stream>>>(
            x, m, WtL + (size_t)l * NH * 256, b_lay + (size_t)l * NH, m);
        short* t = x; x = m; m = t;
    }
    k_out<<<dim3((NSRC + 127) / 128, 2), 256, 0, stream>>>(x, Wob, b_out, out);
}